// Round 5
// baseline (1614.435 us; speedup 1.0000x reference)
//
#include <hip/hip_runtime.h>
#include <math.h>

typedef unsigned short u16;
typedef __attribute__((ext_vector_type(8))) unsigned short u16x8;
typedef __attribute__((ext_vector_type(8))) __bf16 bf16x8;
typedef __attribute__((ext_vector_type(4))) float f32x4;

constexpr int Bc = 2, Sc = 2048, Mc = 1024, Ec = 512, Hc = 8, DH = 64, Fc = 2048, Vc = 8192, Lc = 6;
constexpr int Nc = Bc * Sc;    // 4096 decoder rows
constexpr int NMc = Bc * Mc;   // 2048 encoder rows

__device__ __forceinline__ u16 f2b(float f) {
  __bf16 h = (__bf16)f;
  return __builtin_bit_cast(u16, h);
}

__device__ __forceinline__ f32x4 mfma16(bf16x8 a, bf16x8 b, f32x4 c) {
  return __builtin_amdgcn_mfma_f32_16x16x32_bf16(a, b, c, 0, 0, 0);
}

// ---------------------------------------------------------------------------
__global__ __launch_bounds__(256) void k_cvt(const float* __restrict__ s,
                                             u16* __restrict__ d, int n4) {
  int i = blockIdx.x * 256 + threadIdx.x;
  if (i >= n4) return;
  float4 v = ((const float4*)s)[i];
  unsigned lo = (unsigned)f2b(v.x) | ((unsigned)f2b(v.y) << 16);
  unsigned hi = (unsigned)f2b(v.z) | ((unsigned)f2b(v.w) << 16);
  ((uint2*)d)[i] = make_uint2(lo, hi);
}

// ---------------------------------------------------------------------------
__global__ __launch_bounds__(256) void k_embed(const int* __restrict__ seq,
                                               const float* __restrict__ emb,
                                               const float* __restrict__ pos,
                                               float* __restrict__ x,
                                               u16* __restrict__ xb) {
  int idx = blockIdx.x * 256 + threadIdx.x;
  int row = idx >> 9, e = idx & 511;
  int s = row & (Sc - 1);
  float v = emb[(size_t)seq[row] * Ec + e] + pos[(size_t)s * Ec + e];
  x[idx] = v;
  xb[idx] = f2b(v);
}

// ---------------------------------------------------------------------------
// bf16 MFMA GEMM, swizzled LDS, staged via global_load_lds (pre-swizzled src).
// ---------------------------------------------------------------------------
template <int BM, int BN, int ACT>
__global__ __launch_bounds__(256) void k_gemm_bf(const u16* __restrict__ A,
                                                 const u16* __restrict__ W,
                                                 const float* __restrict__ bias,
                                                 float* __restrict__ C32,
                                                 u16* __restrict__ Cb,
                                                 int K, int Mo) {
  constexpr int WM = BM / 2, WN = BN / 2, FM = WM / 16, FN = WN / 16;
  __shared__ __attribute__((aligned(16))) u16 As[BM * 64];
  __shared__ __attribute__((aligned(16))) u16 Bs[BN * 64];
  const int tid = threadIdx.x;
  const int w = tid >> 6, l = tid & 63, l15 = l & 15, l4 = l >> 4;
  const int lr = l >> 3, lc = l & 7;
  const int wr = (w >> 1) * WM, wc = (w & 1) * WN;
  const size_t row0 = (size_t)blockIdx.y * BM, col0 = (size_t)blockIdx.x * BN;
  const u16* Ab = A + row0 * K;
  const u16* Wb = W + col0 * K;
  f32x4 acc[FM][FN] = {};

  for (int k0 = 0; k0 < K; k0 += 64) {
    __syncthreads();
#pragma unroll
    for (int i = 0; i < BM / 32; ++i) {
      int row = i * 32 + w * 8 + lr;
      int sw = lr ^ ((i * 4 + w) & 7);
      const u16* ga = Ab + (size_t)row * K + k0 + ((lc ^ sw) & 7) * 8;
      __builtin_amdgcn_global_load_lds((const __attribute__((address_space(1))) void*)ga,
          (__attribute__((address_space(3))) void*)((char*)As + (i * 32 + w * 8) * 128), 16, 0, 0);
    }
#pragma unroll
    for (int i = 0; i < BN / 32; ++i) {
      int row = i * 32 + w * 8 + lr;
      int sw = lr ^ ((i * 4 + w) & 7);
      const u16* gw = Wb + (size_t)row * K + k0 + ((lc ^ sw) & 7) * 8;
      __builtin_amdgcn_global_load_lds((const __attribute__((address_space(1))) void*)gw,
          (__attribute__((address_space(3))) void*)((char*)Bs + (i * 32 + w * 8) * 128), 16, 0, 0);
    }
    __syncthreads();
#pragma unroll
    for (int ks = 0; ks < 2; ++ks) {
      bf16x8 af[FM], bfr[FN];
#pragma unroll
      for (int m = 0; m < FM; ++m) {
        int ra = wr + m * 16 + l15;
        int sw = (l15 & 7) ^ ((wr / 8 + 2 * m + (l15 >> 3)) & 7);
        af[m] = *(const bf16x8*)&As[ra * 64 + ((ks * 32 + l4 * 8) ^ (sw * 8))];
      }
#pragma unroll
      for (int n = 0; n < FN; ++n) {
        int rb = wc + n * 16 + l15;
        int sw = (l15 & 7) ^ ((wc / 8 + 2 * n + (l15 >> 3)) & 7);
        bfr[n] = *(const bf16x8*)&Bs[rb * 64 + ((ks * 32 + l4 * 8) ^ (sw * 8))];
      }
#pragma unroll
      for (int m = 0; m < FM; ++m)
#pragma unroll
        for (int n = 0; n < FN; ++n)
          acc[m][n] = mfma16(af[m], bfr[n], acc[m][n]);
    }
  }
#pragma unroll
  for (int n = 0; n < FN; ++n) {
    size_t col = col0 + wc + n * 16 + l15;
    float bv = bias[col];
#pragma unroll
    for (int m = 0; m < FM; ++m)
#pragma unroll
      for (int r = 0; r < 4; ++r) {
        size_t row = row0 + wr + m * 16 + l4 * 4 + r;
        float v = acc[m][n][r] + bv;
        if (ACT) v = 0.5f * v * (1.f + erff(v * 0.70710678118654752f));
        if (C32) C32[row * Mo + col] = v;
        if (Cb) Cb[row * Mo + col] = f2b(v);
      }
  }
}

// ---------------------------------------------------------------------------
// Flash attention, bf16 MFMA, PAIRED q-tiles per block for load balance.
// Grid (nqt/2, H, B), 256 thr = 4 waves; wave w owns rows [qt*64+16w, +16)
// of BOTH q-tiles qa and qb. causal: qa=bx, qb=nqt-1-bx (shared KV prefix);
// non-causal: qa=bx, qb=bx+nqt/2 (both full KV). 3-deep K/V pipeline.
// ---------------------------------------------------------------------------
__global__ __launch_bounds__(256) void k_flash(const u16* __restrict__ Qp, int sq,
                                               const u16* __restrict__ Kp,
                                               const u16* __restrict__ Vp, int skv,
                                               u16* __restrict__ Op, int so,
                                               int Sq, int Sk, int causal) {
  __shared__ __attribute__((aligned(16))) u16 Kst[3][64 * 64];
  __shared__ __attribute__((aligned(16))) u16 Vt[3][64 * 64];   // [d][k]
  __shared__ __attribute__((aligned(16))) u16 PlA[4][16 * 64];
  __shared__ __attribute__((aligned(16))) u16 PlB[4][16 * 64];
  const int tid = threadIdx.x;
  const int w = tid >> 6, l = tid & 63, l15 = l & 15, l4 = l >> 4;
  const int lr = l >> 3, lc = l & 7;
  const int kk2 = tid >> 3, dblk = tid & 7;      // V staging role
  const int nqt = Sq / 64, nkt = Sk / 64;
  const int bx = blockIdx.x;
  const int qaT = bx;
  const int qbT = causal ? (nqt - 1 - bx) : (bx + nqt / 2);
  const int ntA = causal ? (qaT + 1) : nkt;
  const int ntB = causal ? (qbT + 1) : nkt;
  const int h = blockIdx.y, b = blockIdx.z;
  const u16* Qb = Qp + (size_t)b * Sq * sq + h * DH;
  const u16* Kb = Kp + (size_t)b * Sk * skv + h * DH;
  const u16* Vb = Vp + (size_t)b * Sk * skv + h * DH;

  bf16x8 qfA[2], qfB[2];
  {
    const u16* qpA = Qb + (size_t)(qaT * 64 + w * 16 + l15) * sq + l4 * 8;
    qfA[0] = *(const bf16x8*)(qpA);
    qfA[1] = *(const bf16x8*)(qpA + 32);
    const u16* qpB = Qb + (size_t)(qbT * 64 + w * 16 + l15) * sq + l4 * 8;
    qfB[0] = *(const bf16x8*)(qpB);
    qfB[1] = *(const bf16x8*)(qpB + 32);
  }
  bf16x8 onesf;
#pragma unroll
  for (int j = 0; j < 8; ++j) onesf[j] = (__bf16)1.0f;

  f32x4 oaccA[4] = {}, oaccB[4] = {};
  f32x4 lsA = {0.f, 0.f, 0.f, 0.f}, lsB = {0.f, 0.f, 0.f, 0.f};
  float MxA[4], MxB[4];
#pragma unroll
  for (int r = 0; r < 4; ++r) { MxA[r] = -3e38f; MxB[r] = -3e38f; }

  const float CSC = 0.18033688011112042f;  // 1/sqrt(64) * log2(e)

  u16x8 va0, vb0, va1, vb1;
  auto stageK = [&](int buf, int kt) {
#pragma unroll
    for (int i = 0; i < 2; ++i) {
      int row = i * 32 + w * 8 + lr;
      int sw = lr ^ ((i * 4 + w) & 7);
      const u16* src = Kb + (size_t)(kt + row) * skv + ((lc ^ sw) & 7) * 8;
      __builtin_amdgcn_global_load_lds((const __attribute__((address_space(1))) void*)src,
          (__attribute__((address_space(3))) void*)((char*)Kst[buf] + (i * 32 + w * 8) * 128), 16, 0, 0);
    }
  };
  auto loadV = [&](int kt, u16x8& a, u16x8& bv) {
    const u16* vp0 = Vb + (size_t)(kt + 2 * kk2) * skv + dblk * 8;
    a = *(const u16x8*)vp0;
    bv = *(const u16x8*)(vp0 + skv);
  };
  auto writeV = [&](int buf, u16x8 a, u16x8 bv) {
    char* Vb_ = (char*)Vt[buf];
#pragma unroll
    for (int j = 0; j < 8; ++j) {
      int d = dblk * 8 + j;
      int sw = (j ^ dblk) & 7;
      unsigned pk = (unsigned)a[j] | ((unsigned)bv[j] << 16);
      *(unsigned*)(Vb_ + d * 128 + ((4 * kk2) ^ (sw << 4))) = pk;
    }
  };
  // per-state compute pieces (fully inlined; uniform call sites)
  auto qkt = [&](const u16* KstC, const bf16x8 (&qf)[2], f32x4 (&sf)[4]) {
    __builtin_amdgcn_s_setprio(1);
#pragma unroll
    for (int n = 0; n < 4; ++n) {
      int rk = n * 16 + l15;
      int sw = (l15 & 7) ^ ((2 * n + (l15 >> 3)) & 7);
#pragma unroll
      for (int ks = 0; ks < 2; ++ks) {
        bf16x8 kf = *(const bf16x8*)&KstC[rk * 64 + ((ks * 32 + l4 * 8) ^ (sw * 8))];
        sf[n] = mfma16(qf[ks], kf, sf[n]);
      }
    }
    __builtin_amdgcn_s_setprio(0);
  };
  auto softmax = [&](f32x4 (&sf)[4], float (&Mx)[4], f32x4& lsacc, f32x4 (&oacc)[4], u16* Pw) {
    float al[4];
#pragma unroll
    for (int r = 0; r < 4; ++r) {
      float tm = fmaxf(fmaxf(sf[0][r], sf[1][r]), fmaxf(sf[2][r], sf[3][r]));
      tm = fmaxf(tm, __shfl_xor(tm, 1, 64));
      tm = fmaxf(tm, __shfl_xor(tm, 2, 64));
      tm = fmaxf(tm, __shfl_xor(tm, 4, 64));
      tm = fmaxf(tm, __shfl_xor(tm, 8, 64));
      float Mn = fmaxf(Mx[r], tm);
      al[r] = exp2f((Mx[r] - Mn) * CSC);   // exactly 1.0 when no growth
      Mx[r] = Mn;
    }
    float mxc[4];
#pragma unroll
    for (int r = 0; r < 4; ++r) mxc[r] = Mx[r] * CSC;
#pragma unroll
    for (int n = 0; n < 4; ++n)
#pragma unroll
      for (int r = 0; r < 4; ++r) {
        float p = exp2f(sf[n][r] * CSC - mxc[r]);
        int q = l4 * 4 + r;
        int sw = (q & 7) ^ (q >> 3);
        *(u16*)((char*)Pw + q * 128 + ((2 * (n * 16 + l15)) ^ (sw << 4))) = f2b(p);
      }
    bool grow = (al[0] < 1.f) | (al[1] < 1.f) | (al[2] < 1.f) | (al[3] < 1.f);
    if (__any(grow)) {
#pragma unroll
      for (int r = 0; r < 4; ++r) {
        lsacc[r] *= al[r];
#pragma unroll
        for (int n2 = 0; n2 < 4; ++n2) oacc[n2][r] *= al[r];
      }
    }
  };
  auto pv = [&](const u16* Pw, const u16* VtC, f32x4& lsacc, f32x4 (&oacc)[4]) {
    int swp = (l15 & 7) ^ (l15 >> 3);
    __builtin_amdgcn_s_setprio(1);
#pragma unroll
    for (int ks = 0; ks < 2; ++ks) {
      bf16x8 pf = *(const bf16x8*)((char*)Pw + l15 * 128 + ((ks * 64 + l4 * 16) ^ (swp << 4)));
      lsacc = mfma16(pf, onesf, lsacc);
#pragma unroll
      for (int n2 = 0; n2 < 4; ++n2) {
        int rd = n2 * 16 + l15;
        int sw = (l15 & 7) ^ ((2 * n2 + (l15 >> 3)) & 7);
        bf16x8 vf = *(const bf16x8*)((char*)VtC + rd * 128 + ((ks * 64 + l4 * 16) ^ (sw << 4)));
        oacc[n2] = mfma16(pf, vf, oacc[n2]);
      }
    }
    __builtin_amdgcn_s_setprio(0);
  };
  auto maskDiag = [&](f32x4 (&sf)[4], int qT, int t) {
#pragma unroll
    for (int n = 0; n < 4; ++n)
#pragma unroll
      for (int r = 0; r < 4; ++r) {
        int qrow = qT * 64 + w * 16 + l4 * 4 + r;
        int kcol = t * 64 + n * 16 + l15;
        if (kcol > qrow) sf[n][r] = -3e38f;
      }
  };

  // prologue: tiles 0 (and 1) in flight
  stageK(0, 0);
  loadV(0, va0, vb0);
  if (ntB > 1) { stageK(1, 64); loadV(64, va1, vb1); }
  writeV(0, va0, vb0);   // implicit vmcnt wait covers K(0) (older in queue)
  asm volatile("s_waitcnt lgkmcnt(0)" ::: "memory");
  __builtin_amdgcn_sched_barrier(0);
  __builtin_amdgcn_s_barrier();

  u16* PwA = PlA[w];
  u16* PwB = PlB[w];
  int cur = 0;
  for (int t = 0; t < ntB; ++t) {
    const int nxt = (cur == 2) ? 0 : cur + 1;
    const int nn  = (nxt == 2) ? 0 : nxt + 1;
    if (t + 2 < ntB) {
      stageK(nn, (t + 2) * 64);
      if (t & 1) loadV((t + 2) * 64, va1, vb1);
      else       loadV((t + 2) * 64, va0, vb0);
    }
    const u16* KstC = Kst[cur];
    const u16* VtC = Vt[cur];
    const bool actA = (t < ntA);

    f32x4 sfA[4] = {}, sfB[4] = {};
    if (actA) qkt(KstC, qfA, sfA);
    qkt(KstC, qfB, sfB);
    if (causal) {
      if (actA && t == ntA - 1) maskDiag(sfA, qaT, t);
      if (t == ntB - 1) maskDiag(sfB, qbT, t);
    }
    if (actA) softmax(sfA, MxA, lsA, oaccA, PwA);
    softmax(sfB, MxB, lsB, oaccB, PwB);

    // P buffers are wave-private: wave-local LDS drain, no block barrier
    asm volatile("s_waitcnt lgkmcnt(0)" ::: "memory");
    __builtin_amdgcn_sched_barrier(0);

    if (actA) pv(PwA, VtC, lsA, oaccA);
    pv(PwB, VtC, lsB, oaccB);

    if (t + 1 < ntB) {             // write V(t+1) late; its vmcnt wait also
      if (t & 1) writeV(nxt, va0, vb0);   // guarantees K(t+1) landed (older)
      else       writeV(nxt, va1, vb1);
    }
    asm volatile("s_waitcnt lgkmcnt(0)" ::: "memory");
    __builtin_amdgcn_sched_barrier(0);
    __builtin_amdgcn_s_barrier();
    cur = nxt;
  }

  u16* Ob = Op + (size_t)b * Sq * so + h * DH;
#pragma unroll
  for (int n2 = 0; n2 < 4; ++n2)
#pragma unroll
    for (int r = 0; r < 4; ++r) {
      int qrowA = qaT * 64 + w * 16 + l4 * 4 + r;
      Ob[(size_t)qrowA * so + n2 * 16 + l15] = f2b(oaccA[n2][r] / lsA[r]);
      int qrowB = qbT * 64 + w * 16 + l4 * 4 + r;
      Ob[(size_t)qrowB * so + n2 * 16 + l15] = f2b(oaccB[n2][r] / lsB[r]);
    }
}

// ---------------------------------------------------------------------------
__global__ __launch_bounds__(256) void k_res_ln(const float* __restrict__ xin,
                                                const float* __restrict__ rres,
                                                const float* __restrict__ g,
                                                const float* __restrict__ bet,
                                                float* __restrict__ outf,
                                                u16* __restrict__ outb,
                                                int has_res) {
  __shared__ float red[4];
  const int row = blockIdx.x, tid = threadIdx.x;
  const float* xr = xin + (size_t)row * Ec;
  float v0 = xr[tid], v1 = xr[tid + 256];
  if (has_res) {
    const float* rr = rres + (size_t)row * Ec;
    v0 += rr[tid];
    v1 += rr[tid + 256];
  }
  float s = v0 + v1;
#pragma unroll
  for (int o = 32; o; o >>= 1) s += __shfl_down(s, o, 64);
  if ((tid & 63) == 0) red[tid >> 6] = s;
  __syncthreads();
  const float mean = (red[0] + red[1] + red[2] + red[3]) * (1.f / Ec);
  float d0 = v0 - mean, d1 = v1 - mean;
  float vs = d0 * d0 + d1 * d1;
#pragma unroll
  for (int o = 32; o; o >>= 1) vs += __shfl_down(vs, o, 64);
  __syncthreads();
  if ((tid & 63) == 0) red[tid >> 6] = vs;
  __syncthreads();
  const float var = (red[0] + red[1] + red[2] + red[3]) * (1.f / Ec);
  const float inv = rsqrtf(var + 1e-5f);
  float o0 = d0 * inv * g[tid] + bet[tid];
  float o1 = d1 * inv * g[tid + 256] + bet[tid + 256];
  float* orow = outf + (size_t)row * Ec;
  orow[tid] = o0;
  orow[tid + 256] = o1;
  if (outb) {
    u16* brow = outb + (size_t)row * Ec;
    brow[tid] = f2b(o0);
    brow[tid + 256] = f2b(o1);
  }
}

// ---------------------------------------------------------------------------
extern "C" void kernel_launch(void* const* d_in, const int* in_sizes, int n_in,
                              void* d_out, int out_size, void* d_ws, size_t ws_size,
                              hipStream_t stream) {
  const float* encoded      = (const float*)d_in[0];
  const int*   seq          = (const int*)d_in[1];
  const float* input_embed  = (const float*)d_in[2];
  const float* pos_embed    = (const float*)d_in[3];
  const float* output_bias  = (const float*)d_in[4];
  const float* self_in_w    = (const float*)d_in[5];
  const float* self_in_b    = (const float*)d_in[6];
  const float* self_out_w   = (const float*)d_in[7];
  const float* self_out_b   = (const float*)d_in[8];
  const float* cross_in_w   = (const float*)d_in[9];
  const float* cross_in_b   = (const float*)d_in[10];
  const float* cross_out_w  = (const float*)d_in[11];
  const float* cross_out_b  = (const float*)d_in[12];
  const float* self_norm_g  = (const float*)d_in[13];
  const float* self_norm_b  = (const float*)d_in[14];
  const float* cross_norm_g = (const float*)d_in[15];
  const float* cross_norm_b = (const float*)d_in[16];
  const float* mlp_norm_g   = (const float*)d_in[17];
  const float* mlp_norm_b   = (const float*)d_in[18];
  const float* lin1_w       = (const float*)d_in[19];
  const float* lin1_b       = (const float*)d_in[20];
  const float* lin2_w       = (const float*)d_in[21];
  const float* lin2_b       = (const float*)d_in[22];
  const float* final_norm_g = (const float*)d_in[23];
  const float* final_norm_b = (const float*)d_in[24];

  char* oc = (char*)d_out;
  auto take = [&](size_t bytes) { char* p = oc; oc += bytes; return p; };
  u16* wsi  = (u16*)take((size_t)Lc * 3 * Ec * Ec * 2);
  u16* wso  = (u16*)take((size_t)Lc * Ec * Ec * 2);
  u16* wci  = (u16*)take((size_t)Lc * 3 * Ec * Ec * 2);
  u16* wco  = (u16*)take((size_t)Lc * Ec * Ec * 2);
  u16* wl1  = (u16*)take((size_t)Lc * Fc * Ec * 2);
  u16* wl2  = (u16*)take((size_t)Lc * Ec * Fc * 2);
  u16* encb = (u16*)take((size_t)NMc * Ec * 2);
  float* xs  = (float*)take((size_t)Nc * Ec * 4);
  float* ys  = (float*)take((size_t)Nc * Ec * 4);
  float* tmp = (float*)take((size_t)Nc * Ec * 4);
  u16* xbf  = (u16*)take((size_t)Nc * Ec * 2);
  u16* qkvb = (u16*)take((size_t)Nc * 3 * Ec * 2);
  u16* ctxb = (u16*)take((size_t)Nc * Ec * 2);
  u16* qxb  = (u16*)take((size_t)Nc * Ec * 2);
  u16* kvb  = (u16*)take((size_t)NMc * 2 * Ec * 2);
  u16* hbf  = (u16*)take((size_t)Nc * Fc * 2);
  u16* xfb  = (u16*)d_ws;
  u16* embb = (u16*)((char*)d_ws + (size_t)Nc * Ec * 2);

  const dim3 blk(256);
  auto cvt = [&](const float* s, u16* d, size_t n) {
    int n4 = (int)(n / 4);
    k_cvt<<<dim3((n4 + 255) / 256), blk, 0, stream>>>(s, d, n4);
  };
  cvt(self_in_w, wsi, (size_t)Lc * 3 * Ec * Ec);
  cvt(self_out_w, wso, (size_t)Lc * Ec * Ec);
  cvt(cross_in_w, wci, (size_t)Lc * 3 * Ec * Ec);
  cvt(cross_out_w, wco, (size_t)Lc * Ec * Ec);
  cvt(lin1_w, wl1, (size_t)Lc * Fc * Ec);
  cvt(lin2_w, wl2, (size_t)Lc * Ec * Fc);
  cvt(input_embed, embb, (size_t)Vc * Ec);
  cvt(encoded, encb, (size_t)NMc * Ec);

  k_embed<<<dim3(Nc * Ec / 256), blk, 0, stream>>>(seq, input_embed, pos_embed, xs, xbf);

  const dim3 gAttn(Sc / 128, Hc, Bc);   // paired q-tiles: nqt/2 blocks
  for (int l = 0; l < Lc; ++l) {
    const u16* wsi_l = wsi + (size_t)l * 3 * Ec * Ec;
    const u16* wci_l = wci + (size_t)l * 3 * Ec * Ec;
    // self attention
    k_gemm_bf<128, 64, 0><<<dim3(3 * Ec / 64, Nc / 128), blk, 0, stream>>>(
        xbf, wsi_l, self_in_b + (size_t)l * 3 * Ec, nullptr, qkvb, Ec, 3 * Ec);
    k_flash<<<gAttn, blk, 0, stream>>>(qkvb, 3 * Ec, qkvb + Ec, qkvb + 2 * Ec, 3 * Ec,
                                       ctxb, Ec, Sc, Sc, 1);
    k_gemm_bf<64, 64, 0><<<dim3(Ec / 64, Nc / 64), blk, 0, stream>>>(
        ctxb, wso + (size_t)l * Ec * Ec, self_out_b + (size_t)l * Ec, tmp, nullptr, Ec, Ec);
    k_res_ln<<<dim3(Nc), blk, 0, stream>>>(xs, tmp, self_norm_g + (size_t)l * Ec,
                                           self_norm_b + (size_t)l * Ec, ys, xbf, 1);
    // cross attention
    k_gemm_bf<64, 64, 0><<<dim3(Ec / 64, Nc / 64), blk, 0, stream>>>(
        xbf, wci_l, cross_in_b + (size_t)l * 3 * Ec, nullptr, qxb, Ec, Ec);
    k_gemm_bf<64, 64, 0><<<dim3(2 * Ec / 64, NMc / 64), blk, 0, stream>>>(
        encb, wci_l + (size_t)Ec * Ec, cross_in_b + (size_t)l * 3 * Ec + Ec,
        nullptr, kvb, Ec, 2 * Ec);
    k_flash<<<gAttn, blk, 0, stream>>>(qxb, Ec, kvb, kvb + Ec, 2 * Ec,
                                       ctxb, Ec, Sc, Mc, 0);
    k_gemm_bf<64, 64, 0><<<dim3(Ec / 64, Nc / 64), blk, 0, stream>>>(
        ctxb, wco + (size_t)l * Ec * Ec, cross_out_b + (size_t)l * Ec, tmp, nullptr, Ec, Ec);
    k_res_ln<<<dim3(Nc), blk, 0, stream>>>(ys, tmp, cross_norm_g + (size_t)l * Ec,
                                           cross_norm_b + (size_t)l * Ec, xs, xbf, 1);
    // MLP
    k_gemm_bf<128, 64, 1><<<dim3(Fc / 64, Nc / 128), blk, 0, stream>>>(
        xbf, wl1 + (size_t)l * Fc * Ec, lin1_b + (size_t)l * Fc, nullptr, hbf, Ec, Fc);
    k_gemm_bf<64, 64, 0><<<dim3(Ec / 64, Nc / 64), blk, 0, stream>>>(
        hbf, wl2 + (size_t)l * Ec * Fc, lin2_b + (size_t)l * Ec, tmp, nullptr, Fc, Ec);
    k_res_ln<<<dim3(Nc), blk, 0, stream>>>(xs, tmp, mlp_norm_g + (size_t)l * Ec,
                                           mlp_norm_b + (size_t)l * Ec, xs, xbf, 1);
  }

  k_res_ln<<<dim3(Nc), blk, 0, stream>>>(xs, nullptr, final_norm_g, final_norm_b, xs, xfb, 0);
  k_gemm_bf<128, 128, 0><<<dim3(Vc / 128, Nc / 128), blk, 0, stream>>>(
      xfb, embb, output_bias, (float*)d_out, nullptr, Ec, Vc);
}

// Round 6
// 1490.777 us; speedup vs baseline: 1.0829x; 1.0829x over previous
//
#include <hip/hip_runtime.h>
#include <math.h>

typedef unsigned short u16;
typedef __attribute__((ext_vector_type(8))) unsigned short u16x8;
typedef __attribute__((ext_vector_type(8))) __bf16 bf16x8;
typedef __attribute__((ext_vector_type(4))) float f32x4;

constexpr int Bc = 2, Sc = 2048, Mc = 1024, Ec = 512, Hc = 8, DH = 64, Fc = 2048, Vc = 8192, Lc = 6;
constexpr int Nc = Bc * Sc;    // 4096 decoder rows
constexpr int NMc = Bc * Mc;   // 2048 encoder rows

__device__ __forceinline__ u16 f2b(float f) {
  __bf16 h = (__bf16)f;
  return __builtin_bit_cast(u16, h);
}

__device__ __forceinline__ f32x4 mfma16(bf16x8 a, bf16x8 b, f32x4 c) {
  return __builtin_amdgcn_mfma_f32_16x16x32_bf16(a, b, c, 0, 0, 0);
}

// ---------------------------------------------------------------------------
__global__ __launch_bounds__(256) void k_cvt(const float* __restrict__ s,
                                             u16* __restrict__ d, int n4) {
  int i = blockIdx.x * 256 + threadIdx.x;
  if (i >= n4) return;
  float4 v = ((const float4*)s)[i];
  unsigned lo = (unsigned)f2b(v.x) | ((unsigned)f2b(v.y) << 16);
  unsigned hi = (unsigned)f2b(v.z) | ((unsigned)f2b(v.w) << 16);
  ((uint2*)d)[i] = make_uint2(lo, hi);
}

// ---------------------------------------------------------------------------
__global__ __launch_bounds__(256) void k_embed(const int* __restrict__ seq,
                                               const float* __restrict__ emb,
                                               const float* __restrict__ pos,
                                               float* __restrict__ x,
                                               u16* __restrict__ xb) {
  int idx = blockIdx.x * 256 + threadIdx.x;
  int row = idx >> 9, e = idx & 511;
  int s = row & (Sc - 1);
  float v = emb[(size_t)seq[row] * Ec + e] + pos[(size_t)s * Ec + e];
  x[idx] = v;
  xb[idx] = f2b(v);
}

// ---------------------------------------------------------------------------
// bf16 MFMA GEMM, swizzled LDS, staged via global_load_lds (pre-swizzled src).
// ---------------------------------------------------------------------------
template <int BM, int BN, int ACT>
__global__ __launch_bounds__(256) void k_gemm_bf(const u16* __restrict__ A,
                                                 const u16* __restrict__ W,
                                                 const float* __restrict__ bias,
                                                 float* __restrict__ C32,
                                                 u16* __restrict__ Cb,
                                                 int K, int Mo) {
  constexpr int WM = BM / 2, WN = BN / 2, FM = WM / 16, FN = WN / 16;
  __shared__ __attribute__((aligned(16))) u16 As[BM * 64];
  __shared__ __attribute__((aligned(16))) u16 Bs[BN * 64];
  const int tid = threadIdx.x;
  const int w = tid >> 6, l = tid & 63, l15 = l & 15, l4 = l >> 4;
  const int lr = l >> 3, lc = l & 7;
  const int wr = (w >> 1) * WM, wc = (w & 1) * WN;
  const size_t row0 = (size_t)blockIdx.y * BM, col0 = (size_t)blockIdx.x * BN;
  const u16* Ab = A + row0 * K;
  const u16* Wb = W + col0 * K;
  f32x4 acc[FM][FN] = {};

  for (int k0 = 0; k0 < K; k0 += 64) {
    __syncthreads();
#pragma unroll
    for (int i = 0; i < BM / 32; ++i) {
      int sw = lr ^ ((i * 4 + w) & 7);
      int row = i * 32 + w * 8 + lr;
      const u16* ga = Ab + (size_t)row * K + k0 + ((lc ^ sw) & 7) * 8;
      __builtin_amdgcn_global_load_lds((const __attribute__((address_space(1))) void*)ga,
          (__attribute__((address_space(3))) void*)((char*)As + (i * 32 + w * 8) * 128), 16, 0, 0);
    }
#pragma unroll
    for (int i = 0; i < BN / 32; ++i) {
      int sw = lr ^ ((i * 4 + w) & 7);
      int row = i * 32 + w * 8 + lr;
      const u16* gw = Wb + (size_t)row * K + k0 + ((lc ^ sw) & 7) * 8;
      __builtin_amdgcn_global_load_lds((const __attribute__((address_space(1))) void*)gw,
          (__attribute__((address_space(3))) void*)((char*)Bs + (i * 32 + w * 8) * 128), 16, 0, 0);
    }
    __syncthreads();
#pragma unroll
    for (int ks = 0; ks < 2; ++ks) {
      bf16x8 af[FM], bfr[FN];
#pragma unroll
      for (int m = 0; m < FM; ++m) {
        int ra = wr + m * 16 + l15;
        int sw = (l15 & 7) ^ ((wr / 8 + 2 * m + (l15 >> 3)) & 7);
        af[m] = *(const bf16x8*)&As[ra * 64 + ((ks * 32 + l4 * 8) ^ (sw * 8))];
      }
#pragma unroll
      for (int n = 0; n < FN; ++n) {
        int rb = wc + n * 16 + l15;
        int sw = (l15 & 7) ^ ((wc / 8 + 2 * n + (l15 >> 3)) & 7);
        bfr[n] = *(const bf16x8*)&Bs[rb * 64 + ((ks * 32 + l4 * 8) ^ (sw * 8))];
      }
#pragma unroll
      for (int m = 0; m < FM; ++m)
#pragma unroll
        for (int n = 0; n < FN; ++n)
          acc[m][n] = mfma16(af[m], bfr[n], acc[m][n]);
    }
  }
#pragma unroll
  for (int n = 0; n < FN; ++n) {
    size_t col = col0 + wc + n * 16 + l15;
    float bv = bias[col];
#pragma unroll
    for (int m = 0; m < FM; ++m)
#pragma unroll
      for (int r = 0; r < 4; ++r) {
        size_t row = row0 + wr + m * 16 + l4 * 4 + r;
        float v = acc[m][n][r] + bv;
        if (ACT) v = 0.5f * v * (1.f + erff(v * 0.70710678118654752f));
        if (C32) C32[row * Mo + col] = v;
        if (Cb) Cb[row * Mo + col] = f2b(v);
      }
  }
}

// ---------------------------------------------------------------------------
// Flash attention fd2: 512 thr = 8 waves; wave-group ws in {0,1} processes
// even/odd KV tiles (flash-decoding split) with private K/V double buffers
// and independent online softmax; exact (m,l,O) merge via LDS at the end.
// Grid (Sq/64, H, B). Wave wq owns q rows [qt0+16*wq, +16).
// ---------------------------------------------------------------------------
__global__ __launch_bounds__(512, 4) void k_flash(const u16* __restrict__ Qp, int sq,
                                                  const u16* __restrict__ Kp,
                                                  const u16* __restrict__ Vp, int skv,
                                                  u16* __restrict__ Op, int so,
                                                  int Sq, int Sk, int causal) {
  __shared__ __attribute__((aligned(16))) u16 Kst[4][64 * 64];  // [ws*2+buf]
  __shared__ __attribute__((aligned(16))) u16 Vt[4][64 * 64];   // [d][k]
  __shared__ __attribute__((aligned(16))) u16 Pl[8][16 * 64];
  const int tid = threadIdx.x;
  const int w = tid >> 6, l = tid & 63, l15 = l & 15, l4 = l >> 4;
  const int wq = w & 3, ws = w >> 2;
  const int lr = l >> 3, lc = l & 7;
  const int t256 = tid & 255;
  const int kk2 = t256 >> 3, dblk = tid & 7;     // V staging role (per group)
  const int nqt = Sq / 64, nkt = Sk / 64;
  const int qi = causal ? (nqt - 1 - (int)blockIdx.x) : (int)blockIdx.x;
  const int qt0 = qi * 64;
  const int nt = causal ? (qi + 1) : nkt;
  const int NI = (nt + 1) >> 1;                  // pair iterations (both slices)
  const int h = blockIdx.y, b = blockIdx.z;
  const u16* Qb = Qp + (size_t)b * Sq * sq + h * DH;
  const u16* Kb = Kp + (size_t)b * Sk * skv + h * DH;
  const u16* Vb = Vp + (size_t)b * Sk * skv + h * DH;

  bf16x8 qf[2];
  {
    const u16* qp0 = Qb + (size_t)(qt0 + wq * 16 + l15) * sq + l4 * 8;
    qf[0] = *(const bf16x8*)(qp0);
    qf[1] = *(const bf16x8*)(qp0 + 32);
  }
  bf16x8 onesf;
#pragma unroll
  for (int j = 0; j < 8; ++j) onesf[j] = (__bf16)1.0f;

  f32x4 oacc[4] = {};
  f32x4 lsacc = {0.f, 0.f, 0.f, 0.f};
  float Mx[4];
#pragma unroll
  for (int r = 0; r < 4; ++r) Mx[r] = -3e38f;

  const float CSC = 0.18033688011112042f;  // 1/sqrt(64) * log2(e)

  u16x8 va, vbv;
  auto stageK = [&](int slot, int kt) {
#pragma unroll
    for (int i = 0; i < 2; ++i) {
      int sw = lr ^ ((i * 4 + wq) & 7);
      int row = i * 32 + wq * 8 + lr;
      const u16* src = Kb + (size_t)(kt + row) * skv + ((lc ^ sw) & 7) * 8;
      __builtin_amdgcn_global_load_lds((const __attribute__((address_space(1))) void*)src,
          (__attribute__((address_space(3))) void*)((char*)Kst[slot] + (i * 32 + wq * 8) * 128), 16, 0, 0);
    }
  };
  auto loadV = [&](int kt) {
    const u16* vp0 = Vb + (size_t)(kt + 2 * kk2) * skv + dblk * 8;
    va = *(const u16x8*)vp0;
    vbv = *(const u16x8*)(vp0 + skv);
  };
  auto writeV = [&](int slot) {
    char* Vb_ = (char*)Vt[slot];
#pragma unroll
    for (int j = 0; j < 8; ++j) {
      int d = dblk * 8 + j;
      int sw = (j ^ dblk) & 7;
      unsigned pk = (unsigned)va[j] | ((unsigned)vbv[j] << 16);
      *(unsigned*)(Vb_ + d * 128 + ((4 * kk2) ^ (sw << 4))) = pk;
    }
  };

  // prologue: stage tile t0 = ws into buf 0 of this slice
  stageK(ws * 2, ws * 64);
  loadV(ws * 64);
  writeV(ws * 2);   // implicit vmcnt wait covers the K gload_lds (older)
  asm volatile("s_waitcnt lgkmcnt(0)" ::: "memory");
  __builtin_amdgcn_sched_barrier(0);
  __builtin_amdgcn_s_barrier();

  u16* Pw = Pl[w];
  for (int i = 0; i < NI; ++i) {
    const int t = 2 * i + ws;
    const int tn = 2 * (i + 1) + ws;
    const int cur = ws * 2 + (i & 1);
    const int nxt = ws * 2 + ((i + 1) & 1);
    const bool haveNext = tn < nt;
    if (haveNext) {              // issue next same-parity tile early
      stageK(nxt, tn * 64);
      loadV(tn * 64);
    }
    const bool act = t < nt;
    if (act) {
      const u16* KstC = Kst[cur];
      const u16* VtC = Vt[cur];

      // S = Q K^T
      f32x4 sf[4] = {};
      __builtin_amdgcn_s_setprio(1);
#pragma unroll
      for (int n = 0; n < 4; ++n) {
        int rk = n * 16 + l15;
        int sw = (l15 & 7) ^ ((2 * n + (l15 >> 3)) & 7);
#pragma unroll
        for (int ks = 0; ks < 2; ++ks) {
          bf16x8 kf = *(const bf16x8*)&KstC[rk * 64 + ((ks * 32 + l4 * 8) ^ (sw * 8))];
          sf[n] = mfma16(qf[ks], kf, sf[n]);
        }
      }
      __builtin_amdgcn_s_setprio(0);

      if (causal && t == nt - 1) {   // diagonal tile
#pragma unroll
        for (int n = 0; n < 4; ++n)
#pragma unroll
          for (int r = 0; r < 4; ++r) {
            int qrow = qt0 + wq * 16 + l4 * 4 + r;
            int kcol = t * 64 + n * 16 + l15;
            if (kcol > qrow) sf[n][r] = -3e38f;
          }
      }

      // online softmax
      float al[4];
#pragma unroll
      for (int r = 0; r < 4; ++r) {
        float tm = fmaxf(fmaxf(sf[0][r], sf[1][r]), fmaxf(sf[2][r], sf[3][r]));
        tm = fmaxf(tm, __shfl_xor(tm, 1, 64));
        tm = fmaxf(tm, __shfl_xor(tm, 2, 64));
        tm = fmaxf(tm, __shfl_xor(tm, 4, 64));
        tm = fmaxf(tm, __shfl_xor(tm, 8, 64));
        float Mn = fmaxf(Mx[r], tm);
        al[r] = exp2f((Mx[r] - Mn) * CSC);   // exactly 1.0 when no growth
        Mx[r] = Mn;
      }
      float mxc[4];
#pragma unroll
      for (int r = 0; r < 4; ++r) mxc[r] = Mx[r] * CSC;
#pragma unroll
      for (int n = 0; n < 4; ++n)
#pragma unroll
        for (int r = 0; r < 4; ++r) {
          float p = exp2f(sf[n][r] * CSC - mxc[r]);
          int q = l4 * 4 + r;
          int sw = (q & 7) ^ (q >> 3);
          *(u16*)((char*)Pw + q * 128 + ((2 * (n * 16 + l15)) ^ (sw << 4))) = f2b(p);
        }
      bool grow = (al[0] < 1.f) | (al[1] < 1.f) | (al[2] < 1.f) | (al[3] < 1.f);
      if (__any(grow)) {
#pragma unroll
        for (int r = 0; r < 4; ++r) {
          lsacc[r] *= al[r];
#pragma unroll
          for (int n2 = 0; n2 < 4; ++n2) oacc[n2][r] *= al[r];
        }
      }

      // P is wave-private: wave-local LDS drain
      asm volatile("s_waitcnt lgkmcnt(0)" ::: "memory");
      __builtin_amdgcn_sched_barrier(0);

      // O += P V ; rowsum += P * ones
      int swp = (l15 & 7) ^ (l15 >> 3);
      __builtin_amdgcn_s_setprio(1);
#pragma unroll
      for (int ks = 0; ks < 2; ++ks) {
        bf16x8 pf = *(const bf16x8*)((char*)Pw + l15 * 128 + ((ks * 64 + l4 * 16) ^ (swp << 4)));
        lsacc = mfma16(pf, onesf, lsacc);
#pragma unroll
        for (int n2 = 0; n2 < 4; ++n2) {
          int rd = n2 * 16 + l15;
          int sw = (l15 & 7) ^ ((2 * n2 + (l15 >> 3)) & 7);
          bf16x8 vf = *(const bf16x8*)((char*)VtC + rd * 128 + ((ks * 64 + l4 * 16) ^ (sw << 4)));
          oacc[n2] = mfma16(pf, vf, oacc[n2]);
        }
      }
      __builtin_amdgcn_s_setprio(0);
    }

    if (haveNext) writeV(nxt);   // vmcnt wait also guarantees K(tn) landed
    asm volatile("s_waitcnt lgkmcnt(0)" ::: "memory");
    __builtin_amdgcn_sched_barrier(0);
    __builtin_amdgcn_s_barrier();
  }

  // ---- merge the two slices (exact) ----
  __syncthreads();
  float* MG = (float*)&Kst[0][0];          // 24 KB scratch in dead K region
  if (ws == 1) {
    float* p = MG + ((size_t)wq * 64 + l) * 24;
#pragma unroll
    for (int r = 0; r < 4; ++r) { p[r] = Mx[r]; p[4 + r] = lsacc[r]; }
#pragma unroll
    for (int n2 = 0; n2 < 4; ++n2)
#pragma unroll
      for (int r = 0; r < 4; ++r) p[8 + n2 * 4 + r] = oacc[n2][r];
  }
  __syncthreads();
  if (ws == 0) {
    const float* p = MG + ((size_t)wq * 64 + l) * 24;
    u16* Ob = Op + (size_t)b * Sq * so + h * DH;
#pragma unroll
    for (int r = 0; r < 4; ++r) {
      float Mb = p[r], lb = p[4 + r];
      float M = fmaxf(Mx[r], Mb);
      float aA = exp2f((Mx[r] - M) * CSC);
      float aB = exp2f((Mb - M) * CSC);
      float lsum = lsacc[r] * aA + lb * aB;
      int qrow = qt0 + wq * 16 + l4 * 4 + r;
#pragma unroll
      for (int n2 = 0; n2 < 4; ++n2) {
        float o = oacc[n2][r] * aA + p[8 + n2 * 4 + r] * aB;
        Ob[(size_t)qrow * so + n2 * 16 + l15] = f2b(o / lsum);
      }
    }
  }
}

// ---------------------------------------------------------------------------
__global__ __launch_bounds__(256) void k_res_ln(const float* __restrict__ xin,
                                                const float* __restrict__ rres,
                                                const float* __restrict__ g,
                                                const float* __restrict__ bet,
                                                float* __restrict__ outf,
                                                u16* __restrict__ outb,
                                                int has_res) {
  __shared__ float red[4];
  const int row = blockIdx.x, tid = threadIdx.x;
  const float* xr = xin + (size_t)row * Ec;
  float v0 = xr[tid], v1 = xr[tid + 256];
  if (has_res) {
    const float* rr = rres + (size_t)row * Ec;
    v0 += rr[tid];
    v1 += rr[tid + 256];
  }
  float s = v0 + v1;
#pragma unroll
  for (int o = 32; o; o >>= 1) s += __shfl_down(s, o, 64);
  if ((tid & 63) == 0) red[tid >> 6] = s;
  __syncthreads();
  const float mean = (red[0] + red[1] + red[2] + red[3]) * (1.f / Ec);
  float d0 = v0 - mean, d1 = v1 - mean;
  float vs = d0 * d0 + d1 * d1;
#pragma unroll
  for (int o = 32; o; o >>= 1) vs += __shfl_down(vs, o, 64);
  __syncthreads();
  if ((tid & 63) == 0) red[tid >> 6] = vs;
  __syncthreads();
  const float var = (red[0] + red[1] + red[2] + red[3]) * (1.f / Ec);
  const float inv = rsqrtf(var + 1e-5f);
  float o0 = d0 * inv * g[tid] + bet[tid];
  float o1 = d1 * inv * g[tid + 256] + bet[tid + 256];
  float* orow = outf + (size_t)row * Ec;
  orow[tid] = o0;
  orow[tid + 256] = o1;
  if (outb) {
    u16* brow = outb + (size_t)row * Ec;
    brow[tid] = f2b(o0);
    brow[tid + 256] = f2b(o1);
  }
}

// ---------------------------------------------------------------------------
extern "C" void kernel_launch(void* const* d_in, const int* in_sizes, int n_in,
                              void* d_out, int out_size, void* d_ws, size_t ws_size,
                              hipStream_t stream) {
  const float* encoded      = (const float*)d_in[0];
  const int*   seq          = (const int*)d_in[1];
  const float* input_embed  = (const float*)d_in[2];
  const float* pos_embed    = (const float*)d_in[3];
  const float* output_bias  = (const float*)d_in[4];
  const float* self_in_w    = (const float*)d_in[5];
  const float* self_in_b    = (const float*)d_in[6];
  const float* self_out_w   = (const float*)d_in[7];
  const float* self_out_b   = (const float*)d_in[8];
  const float* cross_in_w   = (const float*)d_in[9];
  const float* cross_in_b   = (const float*)d_in[10];
  const float* cross_out_w  = (const float*)d_in[11];
  const float* cross_out_b  = (const float*)d_in[12];
  const float* self_norm_g  = (const float*)d_in[13];
  const float* self_norm_b  = (const float*)d_in[14];
  const float* cross_norm_g = (const float*)d_in[15];
  const float* cross_norm_b = (const float*)d_in[16];
  const float* mlp_norm_g   = (const float*)d_in[17];
  const float* mlp_norm_b   = (const float*)d_in[18];
  const float* lin1_w       = (const float*)d_in[19];
  const float* lin1_b       = (const float*)d_in[20];
  const float* lin2_w       = (const float*)d_in[21];
  const float* lin2_b       = (const float*)d_in[22];
  const float* final_norm_g = (const float*)d_in[23];
  const float* final_norm_b = (const float*)d_in[24];

  char* oc = (char*)d_out;
  auto take = [&](size_t bytes) { char* p = oc; oc += bytes; return p; };
  u16* wsi  = (u16*)take((size_t)Lc * 3 * Ec * Ec * 2);
  u16* wso  = (u16*)take((size_t)Lc * Ec * Ec * 2);
  u16* wci  = (u16*)take((size_t)Lc * 3 * Ec * Ec * 2);
  u16* wco  = (u16*)take((size_t)Lc * Ec * Ec * 2);
  u16* wl1  = (u16*)take((size_t)Lc * Fc * Ec * 2);
  u16* wl2  = (u16*)take((size_t)Lc * Ec * Fc * 2);
  u16* encb = (u16*)take((size_t)NMc * Ec * 2);
  float* xs  = (float*)take((size_t)Nc * Ec * 4);
  float* ys  = (float*)take((size_t)Nc * Ec * 4);
  float* tmp = (float*)take((size_t)Nc * Ec * 4);
  u16* xbf  = (u16*)take((size_t)Nc * Ec * 2);
  u16* qkvb = (u16*)take((size_t)Nc * 3 * Ec * 2);
  u16* ctxb = (u16*)take((size_t)Nc * Ec * 2);
  u16* qxb  = (u16*)take((size_t)Nc * Ec * 2);
  u16* kvb  = (u16*)take((size_t)NMc * 2 * Ec * 2);
  u16* hbf  = (u16*)take((size_t)Nc * Fc * 2);
  u16* xfb  = (u16*)d_ws;
  u16* embb = (u16*)((char*)d_ws + (size_t)Nc * Ec * 2);

  const dim3 blk(256);
  auto cvt = [&](const float* s, u16* d, size_t n) {
    int n4 = (int)(n / 4);
    k_cvt<<<dim3((n4 + 255) / 256), blk, 0, stream>>>(s, d, n4);
  };
  cvt(self_in_w, wsi, (size_t)Lc * 3 * Ec * Ec);
  cvt(self_out_w, wso, (size_t)Lc * Ec * Ec);
  cvt(cross_in_w, wci, (size_t)Lc * 3 * Ec * Ec);
  cvt(cross_out_w, wco, (size_t)Lc * Ec * Ec);
  cvt(lin1_w, wl1, (size_t)Lc * Fc * Ec);
  cvt(lin2_w, wl2, (size_t)Lc * Ec * Fc);
  cvt(input_embed, embb, (size_t)Vc * Ec);
  cvt(encoded, encb, (size_t)NMc * Ec);

  k_embed<<<dim3(Nc * Ec / 256), blk, 0, stream>>>(seq, input_embed, pos_embed, xs, xbf);

  const dim3 gAttn(Sc / 64, Hc, Bc);
  const dim3 blkA(512);
  for (int l = 0; l < Lc; ++l) {
    const u16* wsi_l = wsi + (size_t)l * 3 * Ec * Ec;
    const u16* wci_l = wci + (size_t)l * 3 * Ec * Ec;
    // self attention
    k_gemm_bf<128, 128, 0><<<dim3(3 * Ec / 128, Nc / 128), blk, 0, stream>>>(
        xbf, wsi_l, self_in_b + (size_t)l * 3 * Ec, nullptr, qkvb, Ec, 3 * Ec);
    k_flash<<<gAttn, blkA, 0, stream>>>(qkvb, 3 * Ec, qkvb + Ec, qkvb + 2 * Ec, 3 * Ec,
                                        ctxb, Ec, Sc, Sc, 1);
    k_gemm_bf<128, 64, 0><<<dim3(Ec / 64, Nc / 128), blk, 0, stream>>>(
        ctxb, wso + (size_t)l * Ec * Ec, self_out_b + (size_t)l * Ec, tmp, nullptr, Ec, Ec);
    k_res_ln<<<dim3(Nc), blk, 0, stream>>>(xs, tmp, self_norm_g + (size_t)l * Ec,
                                           self_norm_b + (size_t)l * Ec, ys, xbf, 1);
    // cross attention
    k_gemm_bf<128, 64, 0><<<dim3(Ec / 64, Nc / 128), blk, 0, stream>>>(
        xbf, wci_l, cross_in_b + (size_t)l * 3 * Ec, nullptr, qxb, Ec, Ec);
    k_gemm_bf<128, 64, 0><<<dim3(2 * Ec / 64, NMc / 128), blk, 0, stream>>>(
        encb, wci_l + (size_t)Ec * Ec, cross_in_b + (size_t)l * 3 * Ec + Ec,
        nullptr, kvb, Ec, 2 * Ec);
    k_flash<<<gAttn, blkA, 0, stream>>>(qxb, Ec, kvb, kvb + Ec, 2 * Ec,
                                        ctxb, Ec, Sc, Mc, 0);
    k_gemm_bf<128, 64, 0><<<dim3(Ec / 64, Nc / 128), blk, 0, stream>>>(
        ctxb, wco + (size_t)l * Ec * Ec, cross_out_b + (size_t)l * Ec, tmp, nullptr, Ec, Ec);
    k_res_ln<<<dim3(Nc), blk, 0, stream>>>(ys, tmp, cross_norm_g + (size_t)l * Ec,
                                           cross_norm_b + (size_t)l * Ec, xs, xbf, 1);
    // MLP
    k_gemm_bf<128, 128, 1><<<dim3(Fc / 128, Nc / 128), blk, 0, stream>>>(
        xbf, wl1 + (size_t)l * Fc * Ec, lin1_b + (size_t)l * Fc, nullptr, hbf, Ec, Fc);
    k_gemm_bf<128, 64, 0><<<dim3(Ec / 64, Nc / 128), blk, 0, stream>>>(
        hbf, wl2 + (size_t)l * Ec * Fc, lin2_b + (size_t)l * Ec, tmp, nullptr, Fc, Ec);
    k_res_ln<<<dim3(Nc), blk, 0, stream>>>(xs, tmp, mlp_norm_g + (size_t)l * Ec,
                                           mlp_norm_b + (size_t)l * Ec, xs, xbf, 1);
  }

  k_res_ln<<<dim3(Nc), blk, 0, stream>>>(xs, nullptr, final_norm_g, final_norm_b, xs, xfb, 0);
  k_gemm_bf<128, 128, 0><<<dim3(Vc / 128, Nc / 128), blk, 0, stream>>>(
      xfb, embb, output_bias, (float*)d_out, nullptr, Ec, Vc);
}

// Round 7
// 1401.549 us; speedup vs baseline: 1.1519x; 1.0637x over previous
//
#include <hip/hip_runtime.h>
#include <math.h>

typedef unsigned short u16;
typedef __attribute__((ext_vector_type(8))) unsigned short u16x8;
typedef __attribute__((ext_vector_type(8))) __bf16 bf16x8;
typedef __attribute__((ext_vector_type(4))) float f32x4;

constexpr int Bc = 2, Sc = 2048, Mc = 1024, Ec = 512, Hc = 8, DH = 64, Fc = 2048, Vc = 8192, Lc = 6;
constexpr int Nc = Bc * Sc;    // 4096 decoder rows
constexpr int NMc = Bc * Mc;   // 2048 encoder rows

__device__ __forceinline__ u16 f2b(float f) {
  __bf16 h = (__bf16)f;
  return __builtin_bit_cast(u16, h);
}

__device__ __forceinline__ f32x4 mfma16(bf16x8 a, bf16x8 b, f32x4 c) {
  return __builtin_amdgcn_mfma_f32_16x16x32_bf16(a, b, c, 0, 0, 0);
}

// ---------------------------------------------------------------------------
__global__ __launch_bounds__(256) void k_cvt(const float* __restrict__ s,
                                             u16* __restrict__ d, int n4) {
  int i = blockIdx.x * 256 + threadIdx.x;
  if (i >= n4) return;
  float4 v = ((const float4*)s)[i];
  unsigned lo = (unsigned)f2b(v.x) | ((unsigned)f2b(v.y) << 16);
  unsigned hi = (unsigned)f2b(v.z) | ((unsigned)f2b(v.w) << 16);
  ((uint2*)d)[i] = make_uint2(lo, hi);
}

// ---------------------------------------------------------------------------
__global__ __launch_bounds__(256) void k_embed(const int* __restrict__ seq,
                                               const float* __restrict__ emb,
                                               const float* __restrict__ pos,
                                               float* __restrict__ x,
                                               u16* __restrict__ xb) {
  int idx = blockIdx.x * 256 + threadIdx.x;
  int row = idx >> 9, e = idx & 511;
  int s = row & (Sc - 1);
  float v = emb[(size_t)seq[row] * Ec + e] + pos[(size_t)s * Ec + e];
  x[idx] = v;
  xb[idx] = f2b(v);
}

// ---------------------------------------------------------------------------
// bf16 MFMA GEMM, swizzled LDS, double-buffered staging (one barrier/K-step).
// ---------------------------------------------------------------------------
template <int BM, int BN, int ACT>
__global__ __launch_bounds__(256) void k_gemm_bf(const u16* __restrict__ A,
                                                 const u16* __restrict__ W,
                                                 const float* __restrict__ bias,
                                                 float* __restrict__ C32,
                                                 u16* __restrict__ Cb,
                                                 int K, int Mo) {
  constexpr int WM = BM / 2, WN = BN / 2, FM = WM / 16, FN = WN / 16;
  __shared__ __attribute__((aligned(16))) u16 As[2][BM * 64];
  __shared__ __attribute__((aligned(16))) u16 Bs[2][BN * 64];
  const int tid = threadIdx.x;
  const int w = tid >> 6, l = tid & 63, l15 = l & 15, l4 = l >> 4;
  const int lr = l >> 3, lc = l & 7;
  const int wr = (w >> 1) * WM, wc = (w & 1) * WN;
  const size_t row0 = (size_t)blockIdx.y * BM, col0 = (size_t)blockIdx.x * BN;
  const u16* Ab = A + row0 * K;
  const u16* Wb = W + col0 * K;
  f32x4 acc[FM][FN] = {};

  auto stage = [&](int buf, int k0) {
#pragma unroll
    for (int i = 0; i < BM / 32; ++i) {
      int sw = lr ^ ((i * 4 + w) & 7);
      int row = i * 32 + w * 8 + lr;
      const u16* ga = Ab + (size_t)row * K + k0 + ((lc ^ sw) & 7) * 8;
      __builtin_amdgcn_global_load_lds((const __attribute__((address_space(1))) void*)ga,
          (__attribute__((address_space(3))) void*)((char*)As[buf] + (i * 32 + w * 8) * 128), 16, 0, 0);
    }
#pragma unroll
    for (int i = 0; i < BN / 32; ++i) {
      int sw = lr ^ ((i * 4 + w) & 7);
      int row = i * 32 + w * 8 + lr;
      const u16* gw = Wb + (size_t)row * K + k0 + ((lc ^ sw) & 7) * 8;
      __builtin_amdgcn_global_load_lds((const __attribute__((address_space(1))) void*)gw,
          (__attribute__((address_space(3))) void*)((char*)Bs[buf] + (i * 32 + w * 8) * 128), 16, 0, 0);
    }
  };

  const int nk = K / 64;
  stage(0, 0);
  int cur = 0;
  for (int kt = 0; kt < nk; ++kt) {
    __syncthreads();                 // drains vmcnt: stage(cur) landed
    if (kt + 1 < nk) stage(cur ^ 1, (kt + 1) * 64);   // overlap w/ compute
    const u16* AsC = As[cur];
    const u16* BsC = Bs[cur];
#pragma unroll
    for (int ks = 0; ks < 2; ++ks) {
      bf16x8 af[FM], bfr[FN];
#pragma unroll
      for (int m = 0; m < FM; ++m) {
        int ra = wr + m * 16 + l15;
        int sw = (l15 & 7) ^ ((wr / 8 + 2 * m + (l15 >> 3)) & 7);
        af[m] = *(const bf16x8*)&AsC[ra * 64 + ((ks * 32 + l4 * 8) ^ (sw * 8))];
      }
#pragma unroll
      for (int n = 0; n < FN; ++n) {
        int rb = wc + n * 16 + l15;
        int sw = (l15 & 7) ^ ((wc / 8 + 2 * n + (l15 >> 3)) & 7);
        bfr[n] = *(const bf16x8*)&BsC[rb * 64 + ((ks * 32 + l4 * 8) ^ (sw * 8))];
      }
#pragma unroll
      for (int m = 0; m < FM; ++m)
#pragma unroll
        for (int n = 0; n < FN; ++n)
          acc[m][n] = mfma16(af[m], bfr[n], acc[m][n]);
    }
    cur ^= 1;
  }
#pragma unroll
  for (int n = 0; n < FN; ++n) {
    size_t col = col0 + wc + n * 16 + l15;
    float bv = bias[col];
#pragma unroll
    for (int m = 0; m < FM; ++m)
#pragma unroll
      for (int r = 0; r < 4; ++r) {
        size_t row = row0 + wr + m * 16 + l4 * 4 + r;
        float v = acc[m][n][r] + bv;
        if (ACT) v = 0.5f * v * (1.f + erff(v * 0.70710678118654752f));
        if (C32) C32[row * Mo + col] = v;
        if (Cb) Cb[row * Mo + col] = f2b(v);
      }
  }
}

// ---------------------------------------------------------------------------
// Flash attention fd2: 512 thr = 8 waves; wave-group ws in {0,1} processes
// even/odd KV tiles (flash-decoding split) with private K/V double buffers
// and independent online softmax; exact (m,l,O) merge via LDS at the end.
// Grid (Sq/64, H, B). causal q-tile order flips with batch parity so the two
// blocks co-resident on a CU (ids c, c+256) have complementary work.
// ---------------------------------------------------------------------------
__global__ __launch_bounds__(512, 4) void k_flash(const u16* __restrict__ Qp, int sq,
                                                  const u16* __restrict__ Kp,
                                                  const u16* __restrict__ Vp, int skv,
                                                  u16* __restrict__ Op, int so,
                                                  int Sq, int Sk, int causal) {
  __shared__ __attribute__((aligned(16))) u16 Kst[4][64 * 64];  // [ws*2+buf]
  __shared__ __attribute__((aligned(16))) u16 Vt[4][64 * 64];   // [d][k]
  __shared__ __attribute__((aligned(16))) u16 Pl[8][16 * 64];
  const int tid = threadIdx.x;
  const int w = tid >> 6, l = tid & 63, l15 = l & 15, l4 = l >> 4;
  const int wq = w & 3, ws = w >> 2;
  const int lr = l >> 3, lc = l & 7;
  const int t256 = tid & 255;
  const int kk2 = t256 >> 3, dblk = tid & 7;     // V staging role (per group)
  const int nqt = Sq / 64, nkt = Sk / 64;
  const int h = blockIdx.y, b = blockIdx.z;
  const int bx = blockIdx.x;
  const int qi = causal ? ((b & 1) ? bx : (nqt - 1 - bx)) : bx;
  const int qt0 = qi * 64;
  const int nt = causal ? (qi + 1) : nkt;
  const int NI = (nt + 1) >> 1;                  // pair iterations (both slices)
  const u16* Qb = Qp + (size_t)b * Sq * sq + h * DH;
  const u16* Kb = Kp + (size_t)b * Sk * skv + h * DH;
  const u16* Vb = Vp + (size_t)b * Sk * skv + h * DH;

  bf16x8 qf[2];
  {
    const u16* qp0 = Qb + (size_t)(qt0 + wq * 16 + l15) * sq + l4 * 8;
    qf[0] = *(const bf16x8*)(qp0);
    qf[1] = *(const bf16x8*)(qp0 + 32);
  }
  bf16x8 onesf;
#pragma unroll
  for (int j = 0; j < 8; ++j) onesf[j] = (__bf16)1.0f;

  f32x4 oacc[4] = {};
  f32x4 lsacc = {0.f, 0.f, 0.f, 0.f};
  float Mx[4];
#pragma unroll
  for (int r = 0; r < 4; ++r) Mx[r] = -3e38f;

  const float CSC = 0.18033688011112042f;  // 1/sqrt(64) * log2(e)

  u16x8 va, vbv;
  auto stageK = [&](int slot, int kt) {
#pragma unroll
    for (int i = 0; i < 2; ++i) {
      int sw = lr ^ ((i * 4 + wq) & 7);
      int row = i * 32 + wq * 8 + lr;
      const u16* src = Kb + (size_t)(kt + row) * skv + ((lc ^ sw) & 7) * 8;
      __builtin_amdgcn_global_load_lds((const __attribute__((address_space(1))) void*)src,
          (__attribute__((address_space(3))) void*)((char*)Kst[slot] + (i * 32 + wq * 8) * 128), 16, 0, 0);
    }
  };
  auto loadV = [&](int kt) {
    const u16* vp0 = Vb + (size_t)(kt + 2 * kk2) * skv + dblk * 8;
    va = *(const u16x8*)vp0;
    vbv = *(const u16x8*)(vp0 + skv);
  };
  auto writeV = [&](int slot) {
    char* Vb_ = (char*)Vt[slot];
#pragma unroll
    for (int j = 0; j < 8; ++j) {
      int d = dblk * 8 + j;
      int sw = (j ^ dblk) & 7;
      unsigned pk = (unsigned)va[j] | ((unsigned)vbv[j] << 16);
      *(unsigned*)(Vb_ + d * 128 + ((4 * kk2) ^ (sw << 4))) = pk;
    }
  };

  // prologue: stage tile t0 = ws into buf 0 of this slice
  stageK(ws * 2, ws * 64);
  loadV(ws * 64);
  writeV(ws * 2);   // implicit vmcnt wait covers the K gload_lds (older)
  asm volatile("s_waitcnt lgkmcnt(0)" ::: "memory");
  __builtin_amdgcn_sched_barrier(0);
  __builtin_amdgcn_s_barrier();

  u16* Pw = Pl[w];
  for (int i = 0; i < NI; ++i) {
    const int t = 2 * i + ws;
    const int tn = 2 * (i + 1) + ws;
    const int cur = ws * 2 + (i & 1);
    const int nxt = ws * 2 + ((i + 1) & 1);
    const bool haveNext = tn < nt;
    if (haveNext) {              // issue next same-parity tile early
      stageK(nxt, tn * 64);
      loadV(tn * 64);
    }
    const bool act = t < nt;
    if (act) {
      const u16* KstC = Kst[cur];
      const u16* VtC = Vt[cur];

      // S = Q K^T
      f32x4 sf[4] = {};
      __builtin_amdgcn_s_setprio(1);
#pragma unroll
      for (int n = 0; n < 4; ++n) {
        int rk = n * 16 + l15;
        int sw = (l15 & 7) ^ ((2 * n + (l15 >> 3)) & 7);
#pragma unroll
        for (int ks = 0; ks < 2; ++ks) {
          bf16x8 kf = *(const bf16x8*)&KstC[rk * 64 + ((ks * 32 + l4 * 8) ^ (sw * 8))];
          sf[n] = mfma16(qf[ks], kf, sf[n]);
        }
      }
      __builtin_amdgcn_s_setprio(0);

      if (causal && t == nt - 1) {   // diagonal tile
#pragma unroll
        for (int n = 0; n < 4; ++n)
#pragma unroll
          for (int r = 0; r < 4; ++r) {
            int qrow = qt0 + wq * 16 + l4 * 4 + r;
            int kcol = t * 64 + n * 16 + l15;
            if (kcol > qrow) sf[n][r] = -3e38f;
          }
      }

      // online softmax
      float al[4];
#pragma unroll
      for (int r = 0; r < 4; ++r) {
        float tm = fmaxf(fmaxf(sf[0][r], sf[1][r]), fmaxf(sf[2][r], sf[3][r]));
        tm = fmaxf(tm, __shfl_xor(tm, 1, 64));
        tm = fmaxf(tm, __shfl_xor(tm, 2, 64));
        tm = fmaxf(tm, __shfl_xor(tm, 4, 64));
        tm = fmaxf(tm, __shfl_xor(tm, 8, 64));
        float Mn = fmaxf(Mx[r], tm);
        al[r] = exp2f((Mx[r] - Mn) * CSC);   // exactly 1.0 when no growth
        Mx[r] = Mn;
      }
      float mxc[4];
#pragma unroll
      for (int r = 0; r < 4; ++r) mxc[r] = Mx[r] * CSC;
#pragma unroll
      for (int n = 0; n < 4; ++n)
#pragma unroll
        for (int r = 0; r < 4; ++r) {
          float p = exp2f(sf[n][r] * CSC - mxc[r]);
          int q = l4 * 4 + r;
          int sw = (q & 7) ^ (q >> 3);
          *(u16*)((char*)Pw + q * 128 + ((2 * (n * 16 + l15)) ^ (sw << 4))) = f2b(p);
        }
      bool grow = (al[0] < 1.f) | (al[1] < 1.f) | (al[2] < 1.f) | (al[3] < 1.f);
      if (__any(grow)) {
#pragma unroll
        for (int r = 0; r < 4; ++r) {
          lsacc[r] *= al[r];
#pragma unroll
          for (int n2 = 0; n2 < 4; ++n2) oacc[n2][r] *= al[r];
        }
      }

      // P is wave-private: wave-local LDS drain
      asm volatile("s_waitcnt lgkmcnt(0)" ::: "memory");
      __builtin_amdgcn_sched_barrier(0);

      // O += P V ; rowsum += P * ones
      int swp = (l15 & 7) ^ (l15 >> 3);
      __builtin_amdgcn_s_setprio(1);
#pragma unroll
      for (int ks = 0; ks < 2; ++ks) {
        bf16x8 pf = *(const bf16x8*)((char*)Pw + l15 * 128 + ((ks * 64 + l4 * 16) ^ (swp << 4)));
        lsacc = mfma16(pf, onesf, lsacc);
#pragma unroll
        for (int n2 = 0; n2 < 4; ++n2) {
          int rd = n2 * 16 + l15;
          int sw = (l15 & 7) ^ ((2 * n2 + (l15 >> 3)) & 7);
          bf16x8 vf = *(const bf16x8*)((char*)VtC + rd * 128 + ((ks * 64 + l4 * 16) ^ (sw << 4)));
          oacc[n2] = mfma16(pf, vf, oacc[n2]);
        }
      }
      __builtin_amdgcn_s_setprio(0);
    }

    if (haveNext) writeV(nxt);   // vmcnt wait also guarantees K(tn) landed
    asm volatile("s_waitcnt lgkmcnt(0)" ::: "memory");
    __builtin_amdgcn_sched_barrier(0);
    __builtin_amdgcn_s_barrier();
  }

  // ---- merge the two slices (exact) ----
  __syncthreads();
  float* MG = (float*)&Kst[0][0];          // 24 KB scratch in dead K region
  if (ws == 1) {
    float* p = MG + ((size_t)wq * 64 + l) * 24;
#pragma unroll
    for (int r = 0; r < 4; ++r) { p[r] = Mx[r]; p[4 + r] = lsacc[r]; }
#pragma unroll
    for (int n2 = 0; n2 < 4; ++n2)
#pragma unroll
      for (int r = 0; r < 4; ++r) p[8 + n2 * 4 + r] = oacc[n2][r];
  }
  __syncthreads();
  if (ws == 0) {
    const float* p = MG + ((size_t)wq * 64 + l) * 24;
    u16* Ob = Op + (size_t)b * Sq * so + h * DH;
#pragma unroll
    for (int r = 0; r < 4; ++r) {
      float Mb = p[r], lb = p[4 + r];
      float M = fmaxf(Mx[r], Mb);
      float aA = exp2f((Mx[r] - M) * CSC);
      float aB = exp2f((Mb - M) * CSC);
      float lsum = lsacc[r] * aA + lb * aB;
      int qrow = qt0 + wq * 16 + l4 * 4 + r;
#pragma unroll
      for (int n2 = 0; n2 < 4; ++n2) {
        float o = oacc[n2][r] * aA + p[8 + n2 * 4 + r] * aB;
        Ob[(size_t)qrow * so + n2 * 16 + l15] = f2b(o / lsum);
      }
    }
  }
}

// ---------------------------------------------------------------------------
__global__ __launch_bounds__(256) void k_res_ln(const float* __restrict__ xin,
                                                const float* __restrict__ rres,
                                                const float* __restrict__ g,
                                                const float* __restrict__ bet,
                                                float* __restrict__ outf,
                                                u16* __restrict__ outb,
                                                int has_res) {
  __shared__ float red[4];
  const int row = blockIdx.x, tid = threadIdx.x;
  const float* xr = xin + (size_t)row * Ec;
  float v0 = xr[tid], v1 = xr[tid + 256];
  if (has_res) {
    const float* rr = rres + (size_t)row * Ec;
    v0 += rr[tid];
    v1 += rr[tid + 256];
  }
  float s = v0 + v1;
#pragma unroll
  for (int o = 32; o; o >>= 1) s += __shfl_down(s, o, 64);
  if ((tid & 63) == 0) red[tid >> 6] = s;
  __syncthreads();
  const float mean = (red[0] + red[1] + red[2] + red[3]) * (1.f / Ec);
  float d0 = v0 - mean, d1 = v1 - mean;
  float vs = d0 * d0 + d1 * d1;
#pragma unroll
  for (int o = 32; o; o >>= 1) vs += __shfl_down(vs, o, 64);
  __syncthreads();
  if ((tid & 63) == 0) red[tid >> 6] = vs;
  __syncthreads();
  const float var = (red[0] + red[1] + red[2] + red[3]) * (1.f / Ec);
  const float inv = rsqrtf(var + 1e-5f);
  float o0 = d0 * inv * g[tid] + bet[tid];
  float o1 = d1 * inv * g[tid + 256] + bet[tid + 256];
  float* orow = outf + (size_t)row * Ec;
  orow[tid] = o0;
  orow[tid + 256] = o1;
  if (outb) {
    u16* brow = outb + (size_t)row * Ec;
    brow[tid] = f2b(o0);
    brow[tid + 256] = f2b(o1);
  }
}

// ---------------------------------------------------------------------------
extern "C" void kernel_launch(void* const* d_in, const int* in_sizes, int n_in,
                              void* d_out, int out_size, void* d_ws, size_t ws_size,
                              hipStream_t stream) {
  const float* encoded      = (const float*)d_in[0];
  const int*   seq          = (const int*)d_in[1];
  const float* input_embed  = (const float*)d_in[2];
  const float* pos_embed    = (const float*)d_in[3];
  const float* output_bias  = (const float*)d_in[4];
  const float* self_in_w    = (const float*)d_in[5];
  const float* self_in_b    = (const float*)d_in[6];
  const float* self_out_w   = (const float*)d_in[7];
  const float* self_out_b   = (const float*)d_in[8];
  const float* cross_in_w   = (const float*)d_in[9];
  const float* cross_in_b   = (const float*)d_in[10];
  const float* cross_out_w  = (const float*)d_in[11];
  const float* cross_out_b  = (const float*)d_in[12];
  const float* self_norm_g  = (const float*)d_in[13];
  const float* self_norm_b  = (const float*)d_in[14];
  const float* cross_norm_g = (const float*)d_in[15];
  const float* cross_norm_b = (const float*)d_in[16];
  const float* mlp_norm_g   = (const float*)d_in[17];
  const float* mlp_norm_b   = (const float*)d_in[18];
  const float* lin1_w       = (const float*)d_in[19];
  const float* lin1_b       = (const float*)d_in[20];
  const float* lin2_w       = (const float*)d_in[21];
  const float* lin2_b       = (const float*)d_in[22];
  const float* final_norm_g = (const float*)d_in[23];
  const float* final_norm_b = (const float*)d_in[24];

  char* oc = (char*)d_out;
  auto take = [&](size_t bytes) { char* p = oc; oc += bytes; return p; };
  u16* wsi  = (u16*)take((size_t)Lc * 3 * Ec * Ec * 2);
  u16* wso  = (u16*)take((size_t)Lc * Ec * Ec * 2);
  u16* wci  = (u16*)take((size_t)Lc * 3 * Ec * Ec * 2);
  u16* wco  = (u16*)take((size_t)Lc * Ec * Ec * 2);
  u16* wl1  = (u16*)take((size_t)Lc * Fc * Ec * 2);
  u16* wl2  = (u16*)take((size_t)Lc * Ec * Fc * 2);
  u16* encb = (u16*)take((size_t)NMc * Ec * 2);
  float* xs  = (float*)take((size_t)Nc * Ec * 4);
  float* ys  = (float*)take((size_t)Nc * Ec * 4);
  float* tmp = (float*)take((size_t)Nc * Ec * 4);
  u16* xbf  = (u16*)take((size_t)Nc * Ec * 2);
  u16* qkvb = (u16*)take((size_t)Nc * 3 * Ec * 2);
  u16* ctxb = (u16*)take((size_t)Nc * Ec * 2);
  u16* qxb  = (u16*)take((size_t)Nc * Ec * 2);
  u16* kvb  = (u16*)take((size_t)NMc * 2 * Ec * 2);
  u16* hbf  = (u16*)take((size_t)Nc * Fc * 2);
  u16* xfb  = (u16*)d_ws;
  u16* embb = (u16*)((char*)d_ws + (size_t)Nc * Ec * 2);

  const dim3 blk(256);
  auto cvt = [&](const float* s, u16* d, size_t n) {
    int n4 = (int)(n / 4);
    k_cvt<<<dim3((n4 + 255) / 256), blk, 0, stream>>>(s, d, n4);
  };
  cvt(self_in_w, wsi, (size_t)Lc * 3 * Ec * Ec);
  cvt(self_out_w, wso, (size_t)Lc * Ec * Ec);
  cvt(cross_in_w, wci, (size_t)Lc * 3 * Ec * Ec);
  cvt(cross_out_w, wco, (size_t)Lc * Ec * Ec);
  cvt(lin1_w, wl1, (size_t)Lc * Fc * Ec);
  cvt(lin2_w, wl2, (size_t)Lc * Ec * Fc);
  cvt(input_embed, embb, (size_t)Vc * Ec);
  cvt(encoded, encb, (size_t)NMc * Ec);

  k_embed<<<dim3(Nc * Ec / 256), blk, 0, stream>>>(seq, input_embed, pos_embed, xs, xbf);

  const dim3 gAttn(Sc / 64, Hc, Bc);
  const dim3 blkA(512);
  for (int l = 0; l < Lc; ++l) {
    const u16* wsi_l = wsi + (size_t)l * 3 * Ec * Ec;
    const u16* wci_l = wci + (size_t)l * 3 * Ec * Ec;
    // self attention
    k_gemm_bf<128, 128, 0><<<dim3(3 * Ec / 128, Nc / 128), blk, 0, stream>>>(
        xbf, wsi_l, self_in_b + (size_t)l * 3 * Ec, nullptr, qkvb, Ec, 3 * Ec);
    k_flash<<<gAttn, blkA, 0, stream>>>(qkvb, 3 * Ec, qkvb + Ec, qkvb + 2 * Ec, 3 * Ec,
                                        ctxb, Ec, Sc, Sc, 1);
    k_gemm_bf<128, 64, 0><<<dim3(Ec / 64, Nc / 128), blk, 0, stream>>>(
        ctxb, wso + (size_t)l * Ec * Ec, self_out_b + (size_t)l * Ec, tmp, nullptr, Ec, Ec);
    k_res_ln<<<dim3(Nc), blk, 0, stream>>>(xs, tmp, self_norm_g + (size_t)l * Ec,
                                           self_norm_b + (size_t)l * Ec, ys, xbf, 1);
    // cross attention
    k_gemm_bf<128, 64, 0><<<dim3(Ec / 64, Nc / 128), blk, 0, stream>>>(
        xbf, wci_l, cross_in_b + (size_t)l * 3 * Ec, nullptr, qxb, Ec, Ec);
    k_gemm_bf<128, 64, 0><<<dim3(2 * Ec / 64, NMc / 128), blk, 0, stream>>>(
        encb, wci_l + (size_t)Ec * Ec, cross_in_b + (size_t)l * 3 * Ec + Ec,
        nullptr, kvb, Ec, 2 * Ec);
    k_flash<<<gAttn, blkA, 0, stream>>>(qxb, Ec, kvb, kvb + Ec, 2 * Ec,
                                        ctxb, Ec, Sc, Mc, 0);
    k_gemm_bf<128, 64, 0><<<dim3(Ec / 64, Nc / 128), blk, 0, stream>>>(
        ctxb, wco + (size_t)l * Ec * Ec, cross_out_b + (size_t)l * Ec, tmp, nullptr, Ec, Ec);
    k_res_ln<<<dim3(Nc), blk, 0, stream>>>(ys, tmp, cross_norm_g + (size_t)l * Ec,
                                           cross_norm_b + (size_t)l * Ec, xs, xbf, 1);
    // MLP
    k_gemm_bf<128, 128, 1><<<dim3(Fc / 128, Nc / 128), blk, 0, stream>>>(
        xbf, wl1 + (size_t)l * Fc * Ec, lin1_b + (size_t)l * Fc, nullptr, hbf, Ec, Fc);
    k_gemm_bf<128, 64, 0><<<dim3(Ec / 64, Nc / 128), blk, 0, stream>>>(
        hbf, wl2 + (size_t)l * Ec * Fc, lin2_b + (size_t)l * Ec, tmp, nullptr, Fc, Ec);
    k_res_ln<<<dim3(Nc), blk, 0, stream>>>(xs, tmp, mlp_norm_g + (size_t)l * Ec,
                                           mlp_norm_b + (size_t)l * Ec, xs, xbf, 1);
  }

  k_res_ln<<<dim3(Nc), blk, 0, stream>>>(xs, nullptr, final_norm_g, final_norm_b, xs, xfb, 0);
  k_gemm_bf<128, 128, 0><<<dim3(Vc / 128, Nc / 128), blk, 0, stream>>>(
      xfb, embb, output_bias, (float*)d_out, nullptr, Ec, Vc);
}

// Round 8
// 1177.356 us; speedup vs baseline: 1.3712x; 1.1904x over previous
//
#include <hip/hip_runtime.h>
#include <math.h>

typedef unsigned short u16;
typedef __attribute__((ext_vector_type(8))) unsigned short u16x8;
typedef __attribute__((ext_vector_type(8))) __bf16 bf16x8;
typedef __attribute__((ext_vector_type(4))) float f32x4;

constexpr int Bc = 2, Sc = 2048, Mc = 1024, Ec = 512, Hc = 8, DH = 64, Fc = 2048, Vc = 8192, Lc = 6;
constexpr int Nc = Bc * Sc;    // 4096 decoder rows
constexpr int NMc = Bc * Mc;   // 2048 encoder rows

__device__ __forceinline__ u16 f2b(float f) {
  __bf16 h = (__bf16)f;
  return __builtin_bit_cast(u16, h);
}

__device__ __forceinline__ f32x4 mfma16(bf16x8 a, bf16x8 b, f32x4 c) {
  return __builtin_amdgcn_mfma_f32_16x16x32_bf16(a, b, c, 0, 0, 0);
}

// ---------------------------------------------------------------------------
// One-shot f32->bf16 conversion of all weights/embeddings (8 segments).
// Grid exactly covers total float4 count.
// ---------------------------------------------------------------------------
constexpr int C0 = 1179648;            // self_in  (6*3*512*512/4)
constexpr int C1 = C0 + 393216;        // self_out
constexpr int C2 = C1 + 1179648;       // cross_in
constexpr int C3 = C2 + 393216;        // cross_out
constexpr int C4 = C3 + 1572864;       // lin1
constexpr int C5 = C4 + 1572864;       // lin2
constexpr int C6 = C5 + 1048576;       // input_embed
constexpr int C7 = C6 + 262144;        // encoded  -> total 7602176 = 29696*256

__global__ __launch_bounds__(256) void k_cvt_all(
    const float* __restrict__ s0, const float* __restrict__ s1,
    const float* __restrict__ s2, const float* __restrict__ s3,
    const float* __restrict__ s4, const float* __restrict__ s5,
    const float* __restrict__ s6, const float* __restrict__ s7,
    u16* __restrict__ d0, u16* __restrict__ d1, u16* __restrict__ d2,
    u16* __restrict__ d3, u16* __restrict__ d4, u16* __restrict__ d5,
    u16* __restrict__ d6, u16* __restrict__ d7) {
  int i = blockIdx.x * 256 + threadIdx.x;
  const float* s; u16* d; int off;
  if (i < C3) {
    if (i < C1) { if (i < C0) { s = s0; d = d0; off = i; }
                  else        { s = s1; d = d1; off = i - C0; } }
    else        { if (i < C2) { s = s2; d = d2; off = i - C1; }
                  else        { s = s3; d = d3; off = i - C2; } }
  } else {
    if (i < C5) { if (i < C4) { s = s4; d = d4; off = i - C3; }
                  else        { s = s5; d = d5; off = i - C4; } }
    else        { if (i < C6) { s = s6; d = d6; off = i - C5; }
                  else        { s = s7; d = d7; off = i - C6; } }
  }
  float4 v = ((const float4*)s)[off];
  unsigned lo = (unsigned)f2b(v.x) | ((unsigned)f2b(v.y) << 16);
  unsigned hi = (unsigned)f2b(v.z) | ((unsigned)f2b(v.w) << 16);
  ((uint2*)d)[off] = make_uint2(lo, hi);
}

// ---------------------------------------------------------------------------
__global__ __launch_bounds__(256) void k_embed(const int* __restrict__ seq,
                                               const float* __restrict__ emb,
                                               const float* __restrict__ pos,
                                               float* __restrict__ x,
                                               u16* __restrict__ xb) {
  int idx = blockIdx.x * 256 + threadIdx.x;
  int row = idx >> 9, e = idx & 511;
  int s = row & (Sc - 1);
  float v = emb[(size_t)seq[row] * Ec + e] + pos[(size_t)s * Ec + e];
  x[idx] = v;
  xb[idx] = f2b(v);
}

// ---------------------------------------------------------------------------
// bf16 MFMA GEMM, swizzled LDS, double-buffered staging (one barrier/K-step).
// ---------------------------------------------------------------------------
template <int BM, int BN, int ACT>
__global__ __launch_bounds__(256) void k_gemm_bf(const u16* __restrict__ A,
                                                 const u16* __restrict__ W,
                                                 const float* __restrict__ bias,
                                                 float* __restrict__ C32,
                                                 u16* __restrict__ Cb,
                                                 int K, int Mo) {
  constexpr int WM = BM / 2, WN = BN / 2, FM = WM / 16, FN = WN / 16;
  __shared__ __attribute__((aligned(16))) u16 As[2][BM * 64];
  __shared__ __attribute__((aligned(16))) u16 Bs[2][BN * 64];
  const int tid = threadIdx.x;
  const int w = tid >> 6, l = tid & 63, l15 = l & 15, l4 = l >> 4;
  const int lr = l >> 3, lc = l & 7;
  const int wr = (w >> 1) * WM, wc = (w & 1) * WN;
  const size_t row0 = (size_t)blockIdx.y * BM, col0 = (size_t)blockIdx.x * BN;
  const u16* Ab = A + row0 * K;
  const u16* Wb = W + col0 * K;
  f32x4 acc[FM][FN] = {};

  auto stage = [&](int buf, int k0) {
#pragma unroll
    for (int i = 0; i < BM / 32; ++i) {
      int sw = lr ^ ((i * 4 + w) & 7);
      int row = i * 32 + w * 8 + lr;
      const u16* ga = Ab + (size_t)row * K + k0 + ((lc ^ sw) & 7) * 8;
      __builtin_amdgcn_global_load_lds((const __attribute__((address_space(1))) void*)ga,
          (__attribute__((address_space(3))) void*)((char*)As[buf] + (i * 32 + w * 8) * 128), 16, 0, 0);
    }
#pragma unroll
    for (int i = 0; i < BN / 32; ++i) {
      int sw = lr ^ ((i * 4 + w) & 7);
      int row = i * 32 + w * 8 + lr;
      const u16* gw = Wb + (size_t)row * K + k0 + ((lc ^ sw) & 7) * 8;
      __builtin_amdgcn_global_load_lds((const __attribute__((address_space(1))) void*)gw,
          (__attribute__((address_space(3))) void*)((char*)Bs[buf] + (i * 32 + w * 8) * 128), 16, 0, 0);
    }
  };

  const int nk = K / 64;
  stage(0, 0);
  int cur = 0;
  for (int kt = 0; kt < nk; ++kt) {
    __syncthreads();                 // drains vmcnt: stage(cur) landed
    if (kt + 1 < nk) stage(cur ^ 1, (kt + 1) * 64);   // overlap w/ compute
    const u16* AsC = As[cur];
    const u16* BsC = Bs[cur];
#pragma unroll
    for (int ks = 0; ks < 2; ++ks) {
      bf16x8 af[FM], bfr[FN];
#pragma unroll
      for (int m = 0; m < FM; ++m) {
        int ra = wr + m * 16 + l15;
        int sw = (l15 & 7) ^ ((wr / 8 + 2 * m + (l15 >> 3)) & 7);
        af[m] = *(const bf16x8*)&AsC[ra * 64 + ((ks * 32 + l4 * 8) ^ (sw * 8))];
      }
#pragma unroll
      for (int n = 0; n < FN; ++n) {
        int rb = wc + n * 16 + l15;
        int sw = (l15 & 7) ^ ((wc / 8 + 2 * n + (l15 >> 3)) & 7);
        bfr[n] = *(const bf16x8*)&BsC[rb * 64 + ((ks * 32 + l4 * 8) ^ (sw * 8))];
      }
#pragma unroll
      for (int m = 0; m < FM; ++m)
#pragma unroll
        for (int n = 0; n < FN; ++n)
          acc[m][n] = mfma16(af[m], bfr[n], acc[m][n]);
    }
    cur ^= 1;
  }
#pragma unroll
  for (int n = 0; n < FN; ++n) {
    size_t col = col0 + wc + n * 16 + l15;
    float bv = bias[col];
#pragma unroll
    for (int m = 0; m < FM; ++m)
#pragma unroll
      for (int r = 0; r < 4; ++r) {
        size_t row = row0 + wr + m * 16 + l4 * 4 + r;
        float v = acc[m][n][r] + bv;
        if (ACT) v = 0.5f * v * (1.f + erff(v * 0.70710678118654752f));
        if (C32) C32[row * Mo + col] = v;
        if (Cb) Cb[row * Mo + col] = f2b(v);
      }
  }
}

// ---------------------------------------------------------------------------
// Flash attention fd2 + swapped QK^T. 512 thr = 8 waves (4 q-waves x 2 kv
// slices). S^T = mfma(K,Q): lane's softmax row is q = l&15 -> in-lane max/sum
// + 2 shfl_xor. P packed-dword to LDS, PV as before. Exact slice merge in LDS.
// causal q-tile order flips with batch parity for CU load balance.
// ---------------------------------------------------------------------------
__global__ __launch_bounds__(512, 4) void k_flash(const u16* __restrict__ Qp, int sq,
                                                  const u16* __restrict__ Kp,
                                                  const u16* __restrict__ Vp, int skv,
                                                  u16* __restrict__ Op, int so,
                                                  int Sq, int Sk, int causal) {
  __shared__ __attribute__((aligned(16))) u16 Kst[4][64 * 64];  // [ws*2+buf]
  __shared__ __attribute__((aligned(16))) u16 Vt[4][64 * 64];   // [d][k]
  __shared__ __attribute__((aligned(16))) u16 Pl[8][16 * 64];
  const int tid = threadIdx.x;
  const int w = tid >> 6, l = tid & 63, l15 = l & 15, l4 = l >> 4;
  const int wq = w & 3, ws = w >> 2;
  const int lr = l >> 3, lc = l & 7;
  const int t256 = tid & 255;
  const int kk2 = t256 >> 3, dblk = tid & 7;     // V staging role (per group)
  const int nqt = Sq / 64, nkt = Sk / 64;
  const int h = blockIdx.y, b = blockIdx.z;
  const int bx = blockIdx.x;
  const int qi = causal ? ((b & 1) ? bx : (nqt - 1 - bx)) : bx;
  const int qt0 = qi * 64;
  const int nt = causal ? (qi + 1) : nkt;
  const int NI = (nt + 1) >> 1;
  const u16* Qb = Qp + (size_t)b * Sq * sq + h * DH;
  const u16* Kb = Kp + (size_t)b * Sk * skv + h * DH;
  const u16* Vb = Vp + (size_t)b * Sk * skv + h * DH;
  const int qg = qt0 + wq * 16 + l15;            // this lane's softmax q row

  bf16x8 qf[2];
  {
    const u16* qp0 = Qb + (size_t)qg * sq + l4 * 8;
    qf[0] = *(const bf16x8*)(qp0);
    qf[1] = *(const bf16x8*)(qp0 + 32);
  }

  f32x4 oacc[4] = {};
  float ls = 0.f, Mx = -3e38f;
  const float CSC = 0.18033688011112042f;        // 1/sqrt(64) * log2(e)
  const int swp = (l15 & 7) ^ (l15 >> 3);

  u16x8 va, vbv;
  auto stageK = [&](int slot, int kt) {
#pragma unroll
    for (int i = 0; i < 2; ++i) {
      int sw = lr ^ ((i * 4 + wq) & 7);
      int row = i * 32 + wq * 8 + lr;
      const u16* src = Kb + (size_t)(kt + row) * skv + ((lc ^ sw) & 7) * 8;
      __builtin_amdgcn_global_load_lds((const __attribute__((address_space(1))) void*)src,
          (__attribute__((address_space(3))) void*)((char*)Kst[slot] + (i * 32 + wq * 8) * 128), 16, 0, 0);
    }
  };
  auto loadV = [&](int kt) {
    const u16* vp0 = Vb + (size_t)(kt + 2 * kk2) * skv + dblk * 8;
    va = *(const u16x8*)vp0;
    vbv = *(const u16x8*)(vp0 + skv);
  };
  auto writeV = [&](int slot) {
    char* Vb_ = (char*)Vt[slot];
#pragma unroll
    for (int j = 0; j < 8; ++j) {
      int d = dblk * 8 + j;
      int sw = (j ^ dblk) & 7;
      unsigned pk = (unsigned)va[j] | ((unsigned)vbv[j] << 16);
      *(unsigned*)(Vb_ + d * 128 + ((4 * kk2) ^ (sw << 4))) = pk;
    }
  };

  // prologue: stage tile t0 = ws into buf 0 of this slice
  stageK(ws * 2, ws * 64);
  loadV(ws * 64);
  writeV(ws * 2);   // implicit vmcnt wait covers the K gload_lds (older)
  asm volatile("s_waitcnt lgkmcnt(0)" ::: "memory");
  __builtin_amdgcn_sched_barrier(0);
  __builtin_amdgcn_s_barrier();

  u16* Pw = Pl[w];
  for (int i = 0; i < NI; ++i) {
    const int t = 2 * i + ws;
    const int tn = t + 2;
    const int cur = ws * 2 + (i & 1);
    const int nxt = ws * 2 + ((i + 1) & 1);
    const bool haveNext = tn < nt;
    if (haveNext) {              // issue next same-parity tile early
      stageK(nxt, tn * 64);
      loadV(tn * 64);
    }
    if (t < nt) {
      const u16* KstC = Kst[cur];
      const u16* VtC = Vt[cur];

      // S^T = K Q^T : sf[n][r] = S[k = t*64 + n*16 + l4*4 + r][q = qg]
      f32x4 sf[4] = {};
      __builtin_amdgcn_s_setprio(1);
#pragma unroll
      for (int n = 0; n < 4; ++n) {
        int rk = n * 16 + l15;
        int sw = (l15 & 7) ^ ((2 * n + (l15 >> 3)) & 7);
#pragma unroll
        for (int ks = 0; ks < 2; ++ks) {
          bf16x8 kf = *(const bf16x8*)&KstC[rk * 64 + ((ks * 32 + l4 * 8) ^ (sw * 8))];
          sf[n] = mfma16(kf, qf[ks], sf[n]);   // swapped: A=K, B=Q
        }
      }
      __builtin_amdgcn_s_setprio(0);

      if (causal && t == nt - 1) {   // diagonal tile: mask k > q
#pragma unroll
        for (int n = 0; n < 4; ++n)
#pragma unroll
          for (int r = 0; r < 4; ++r) {
            int kcol = t * 64 + n * 16 + l4 * 4 + r;
            if (kcol > qg) sf[n][r] = -3e38f;
          }
      }

      // in-register online softmax for q = qg
      float tm = fmaxf(fmaxf(fmaxf(sf[0][0], sf[0][1]), fmaxf(sf[0][2], sf[0][3])),
                       fmaxf(fmaxf(sf[1][0], sf[1][1]), fmaxf(sf[1][2], sf[1][3])));
      tm = fmaxf(tm, fmaxf(fmaxf(fmaxf(sf[2][0], sf[2][1]), fmaxf(sf[2][2], sf[2][3])),
                           fmaxf(fmaxf(sf[3][0], sf[3][1]), fmaxf(sf[3][2], sf[3][3]))));
      tm = fmaxf(tm, __shfl_xor(tm, 16, 64));
      tm = fmaxf(tm, __shfl_xor(tm, 32, 64));
      float Mn = fmaxf(Mx, tm);
      float al = exp2f((Mx - Mn) * CSC);       // exactly 1.0 when no growth
      Mx = Mn;
      float mxc = Mx * CSC;

      float rs = 0.f;
#pragma unroll
      for (int n = 0; n < 4; ++n) {
        float p0 = exp2f(sf[n][0] * CSC - mxc);
        float p1 = exp2f(sf[n][1] * CSC - mxc);
        float p2 = exp2f(sf[n][2] * CSC - mxc);
        float p3 = exp2f(sf[n][3] * CSC - mxc);
        rs += (p0 + p1) + (p2 + p3);
        unsigned w0 = (unsigned)f2b(p0) | ((unsigned)f2b(p1) << 16);
        unsigned w1 = (unsigned)f2b(p2) | ((unsigned)f2b(p3) << 16);
        int bb = (n * 32 + l4 * 8) ^ (swp << 4);
        *(unsigned*)((char*)Pw + l15 * 128 + bb) = w0;
        *(unsigned*)((char*)Pw + l15 * 128 + bb + 4) = w1;
      }
      rs += __shfl_xor(rs, 16, 64);
      rs += __shfl_xor(rs, 32, 64);
      ls = ls * al + rs;

      if (__any(al < 1.f)) {       // rescale O (q domain = l4*4+r rows)
        float a0 = __shfl(al, l4 * 4 + 0, 64);
        float a1 = __shfl(al, l4 * 4 + 1, 64);
        float a2 = __shfl(al, l4 * 4 + 2, 64);
        float a3 = __shfl(al, l4 * 4 + 3, 64);
#pragma unroll
        for (int n2 = 0; n2 < 4; ++n2) {
          oacc[n2][0] *= a0; oacc[n2][1] *= a1;
          oacc[n2][2] *= a2; oacc[n2][3] *= a3;
        }
      }

      // P is wave-private: wave-local LDS drain
      asm volatile("s_waitcnt lgkmcnt(0)" ::: "memory");
      __builtin_amdgcn_sched_barrier(0);

      // O += P V
      __builtin_amdgcn_s_setprio(1);
#pragma unroll
      for (int ks = 0; ks < 2; ++ks) {
        bf16x8 pf = *(const bf16x8*)((char*)Pw + l15 * 128 + ((ks * 64 + l4 * 16) ^ (swp << 4)));
#pragma unroll
        for (int n2 = 0; n2 < 4; ++n2) {
          int rd = n2 * 16 + l15;
          int sw = (l15 & 7) ^ ((2 * n2 + (l15 >> 3)) & 7);
          bf16x8 vf = *(const bf16x8*)((char*)VtC + rd * 128 + ((ks * 64 + l4 * 16) ^ (sw << 4)));
          oacc[n2] = mfma16(pf, vf, oacc[n2]);
        }
      }
      __builtin_amdgcn_s_setprio(0);
    }

    if (haveNext) writeV(nxt);   // vmcnt wait also guarantees K(tn) landed
    asm volatile("s_waitcnt lgkmcnt(0)" ::: "memory");
    __builtin_amdgcn_sched_barrier(0);
    __builtin_amdgcn_s_barrier();
  }

  // ---- merge the two kv-slices (exact, f32) ----
  __syncthreads();
  float* OB = (float*)&Kst[0][0];   // [64 q][64 d] f32 = 16 KB (dead K region)
  float* ML = (float*)&Vt[0][0];    // m: [2][64], l: [2][64] (dead V region)
  if (l4 == 0) {
    ML[ws * 64 + wq * 16 + l15] = Mx;
    ML[128 + ws * 64 + wq * 16 + l15] = ls;
  }
  if (ws == 1) {
#pragma unroll
    for (int n2 = 0; n2 < 4; ++n2)
#pragma unroll
      for (int r = 0; r < 4; ++r)
        OB[(wq * 16 + l4 * 4 + r) * 64 + n2 * 16 + l15] = oacc[n2][r];
  }
  __syncthreads();
  if (ws == 0) {
    u16* Ob = Op + (size_t)b * Sq * so + h * DH;
#pragma unroll
    for (int r = 0; r < 4; ++r) {
      int qs = wq * 16 + l4 * 4 + r;
      float mA = ML[qs], mB = ML[64 + qs];
      float lA = ML[128 + qs], lB = ML[192 + qs];
      float M = fmaxf(mA, mB);
      float aA = exp2f((mA - M) * CSC);
      float aB = exp2f((mB - M) * CSC);
      float inv = 1.f / (lA * aA + lB * aB);
      int qrow = qt0 + qs;
#pragma unroll
      for (int n2 = 0; n2 < 4; ++n2) {
        float o = (oacc[n2][r] * aA + OB[qs * 64 + n2 * 16 + l15] * aB) * inv;
        Ob[(size_t)qrow * so + n2 * 16 + l15] = f2b(o);
      }
    }
  }
}

// ---------------------------------------------------------------------------
// Fused residual + LayerNorm (fp32), float2-vectorized, dual fp32/bf16 out.
// ---------------------------------------------------------------------------
__global__ __launch_bounds__(256) void k_res_ln(const float* __restrict__ xin,
                                                const float* __restrict__ rres,
                                                const float* __restrict__ g,
                                                const float* __restrict__ bet,
                                                float* __restrict__ outf,
                                                u16* __restrict__ outb,
                                                int has_res) {
  __shared__ float red[4];
  const int row = blockIdx.x, tid = threadIdx.x;
  const float2* xr = (const float2*)(xin + (size_t)row * Ec);
  float2 v = xr[tid];
  if (has_res) {
    float2 rv = ((const float2*)(rres + (size_t)row * Ec))[tid];
    v.x += rv.x; v.y += rv.y;
  }
  float s = v.x + v.y;
#pragma unroll
  for (int o = 32; o; o >>= 1) s += __shfl_down(s, o, 64);
  if ((tid & 63) == 0) red[tid >> 6] = s;
  __syncthreads();
  const float mean = (red[0] + red[1] + red[2] + red[3]) * (1.f / Ec);
  float d0 = v.x - mean, d1 = v.y - mean;
  float vs = d0 * d0 + d1 * d1;
#pragma unroll
  for (int o = 32; o; o >>= 1) vs += __shfl_down(vs, o, 64);
  __syncthreads();
  if ((tid & 63) == 0) red[tid >> 6] = vs;
  __syncthreads();
  const float var = (red[0] + red[1] + red[2] + red[3]) * (1.f / Ec);
  const float inv = rsqrtf(var + 1e-5f);
  float2 gv = ((const float2*)g)[tid];
  float2 bv = ((const float2*)bet)[tid];
  float o0 = d0 * inv * gv.x + bv.x;
  float o1 = d1 * inv * gv.y + bv.y;
  ((float2*)(outf + (size_t)row * Ec))[tid] = make_float2(o0, o1);
  if (outb) {
    unsigned pk = (unsigned)f2b(o0) | ((unsigned)f2b(o1) << 16);
    ((unsigned*)(outb + (size_t)row * Ec))[tid] = pk;
  }
}

// ---------------------------------------------------------------------------
extern "C" void kernel_launch(void* const* d_in, const int* in_sizes, int n_in,
                              void* d_out, int out_size, void* d_ws, size_t ws_size,
                              hipStream_t stream) {
  const float* encoded      = (const float*)d_in[0];
  const int*   seq          = (const int*)d_in[1];
  const float* input_embed  = (const float*)d_in[2];
  const float* pos_embed    = (const float*)d_in[3];
  const float* output_bias  = (const float*)d_in[4];
  const float* self_in_w    = (const float*)d_in[5];
  const float* self_in_b    = (const float*)d_in[6];
  const float* self_out_w   = (const float*)d_in[7];
  const float* self_out_b   = (const float*)d_in[8];
  const float* cross_in_w   = (const float*)d_in[9];
  const float* cross_in_b   = (const float*)d_in[10];
  const float* cross_out_w  = (const float*)d_in[11];
  const float* cross_out_b  = (const float*)d_in[12];
  const float* self_norm_g  = (const float*)d_in[13];
  const float* self_norm_b  = (const float*)d_in[14];
  const float* cross_norm_g = (const float*)d_in[15];
  const float* cross_norm_b = (const float*)d_in[16];
  const float* mlp_norm_g   = (const float*)d_in[17];
  const float* mlp_norm_b   = (const float*)d_in[18];
  const float* lin1_w       = (const float*)d_in[19];
  const float* lin1_b       = (const float*)d_in[20];
  const float* lin2_w       = (const float*)d_in[21];
  const float* lin2_b       = (const float*)d_in[22];
  const float* final_norm_g = (const float*)d_in[23];
  const float* final_norm_b = (const float*)d_in[24];

  char* oc = (char*)d_out;
  auto take = [&](size_t bytes) { char* p = oc; oc += bytes; return p; };
  u16* wsi  = (u16*)take((size_t)Lc * 3 * Ec * Ec * 2);
  u16* wso  = (u16*)take((size_t)Lc * Ec * Ec * 2);
  u16* wci  = (u16*)take((size_t)Lc * 3 * Ec * Ec * 2);
  u16* wco  = (u16*)take((size_t)Lc * Ec * Ec * 2);
  u16* wl1  = (u16*)take((size_t)Lc * Fc * Ec * 2);
  u16* wl2  = (u16*)take((size_t)Lc * Ec * Fc * 2);
  u16* encb = (u16*)take((size_t)NMc * Ec * 2);
  float* xs  = (float*)take((size_t)Nc * Ec * 4);
  float* ys  = (float*)take((size_t)Nc * Ec * 4);
  float* tmp = (float*)take((size_t)Nc * Ec * 4);
  u16* xbf  = (u16*)take((size_t)Nc * Ec * 2);
  u16* qkvb = (u16*)take((size_t)Nc * 3 * Ec * 2);
  u16* ctxb = (u16*)take((size_t)Nc * Ec * 2);
  u16* qxb  = (u16*)take((size_t)Nc * Ec * 2);
  u16* kvb  = (u16*)take((size_t)NMc * 2 * Ec * 2);
  u16* hbf  = (u16*)take((size_t)Nc * Fc * 2);
  u16* xfb  = (u16*)d_ws;
  u16* embb = (u16*)((char*)d_ws + (size_t)Nc * Ec * 2);

  const dim3 blk(256);
  k_cvt_all<<<dim3(29696), blk, 0, stream>>>(
      self_in_w, self_out_w, cross_in_w, cross_out_w, lin1_w, lin2_w,
      input_embed, encoded, wsi, wso, wci, wco, wl1, wl2, embb, encb);

  k_embed<<<dim3(Nc * Ec / 256), blk, 0, stream>>>(seq, input_embed, pos_embed, xs, xbf);

  const dim3 gAttn(Sc / 64, Hc, Bc);
  const dim3 blkA(512);
  for (int l = 0; l < Lc; ++l) {
    const u16* wsi_l = wsi + (size_t)l * 3 * Ec * Ec;
    const u16* wci_l = wci + (size_t)l * 3 * Ec * Ec;
    // self attention
    k_gemm_bf<128, 64, 0><<<dim3(3 * Ec / 64, Nc / 128), blk, 0, stream>>>(
        xbf, wsi_l, self_in_b + (size_t)l * 3 * Ec, nullptr, qkvb, Ec, 3 * Ec);
    k_flash<<<gAttn, blkA, 0, stream>>>(qkvb, 3 * Ec, qkvb + Ec, qkvb + 2 * Ec, 3 * Ec,
                                        ctxb, Ec, Sc, Sc, 1);
    k_gemm_bf<64, 64, 0><<<dim3(Ec / 64, Nc / 64), blk, 0, stream>>>(
        ctxb, wso + (size_t)l * Ec * Ec, self_out_b + (size_t)l * Ec, tmp, nullptr, Ec, Ec);
    k_res_ln<<<dim3(Nc), blk, 0, stream>>>(xs, tmp, self_norm_g + (size_t)l * Ec,
                                           self_norm_b + (size_t)l * Ec, ys, xbf, 1);
    // cross attention
    k_gemm_bf<64, 64, 0><<<dim3(Ec / 64, Nc / 64), blk, 0, stream>>>(
        xbf, wci_l, cross_in_b + (size_t)l * 3 * Ec, nullptr, qxb, Ec, Ec);
    k_gemm_bf<64, 64, 0><<<dim3(2 * Ec / 64, NMc / 64), blk, 0, stream>>>(
        encb, wci_l + (size_t)Ec * Ec, cross_in_b + (size_t)l * 3 * Ec + Ec,
        nullptr, kvb, Ec, 2 * Ec);
    k_flash<<<gAttn, blkA, 0, stream>>>(qxb, Ec, kvb, kvb + Ec, 2 * Ec,
                                        ctxb, Ec, Sc, Mc, 0);
    k_gemm_bf<64, 64, 0><<<dim3(Ec / 64, Nc / 64), blk, 0, stream>>>(
        ctxb, wco + (size_t)l * Ec * Ec, cross_out_b + (size_t)l * Ec, tmp, nullptr, Ec, Ec);
    k_res_ln<<<dim3(Nc), blk, 0, stream>>>(ys, tmp, cross_norm_g + (size_t)l * Ec,
                                           cross_norm_b + (size_t)l * Ec, xs, xbf, 1);
    // MLP
    k_gemm_bf<128, 128, 1><<<dim3(Fc / 128, Nc / 128), blk, 0, stream>>>(
        xbf, wl1 + (size_t)l * Fc * Ec, lin1_b + (size_t)l * Fc, nullptr, hbf, Ec, Fc);
    k_gemm_bf<64, 64, 0><<<dim3(Ec / 64, Nc / 64), blk, 0, stream>>>(
        hbf, wl2 + (size_t)l * Ec * Fc, lin2_b + (size_t)l * Ec, tmp, nullptr, Fc, Ec);
    k_res_ln<<<dim3(Nc), blk, 0, stream>>>(xs, tmp, mlp_norm_g + (size_t)l * Ec,
                                           mlp_norm_b + (size_t)l * Ec, xs, xbf, 1);
  }

  k_res_ln<<<dim3(Nc), blk, 0, stream>>>(xs, nullptr, final_norm_g, final_norm_b, xs, xfb, 0);
  k_gemm_bf<128, 128, 0><<<dim3(Vc / 128, Nc / 128), blk, 0, stream>>>(
      xfb, embb, output_bias, (float*)d_out, nullptr, Ec, Vc);
}

// Round 11
// 1140.588 us; speedup vs baseline: 1.4154x; 1.0322x over previous
//
#include <hip/hip_runtime.h>
#include <math.h>

typedef unsigned short u16;
typedef __attribute__((ext_vector_type(8))) unsigned short u16x8;
typedef __attribute__((ext_vector_type(8))) __bf16 bf16x8;
typedef __attribute__((ext_vector_type(4))) float f32x4;

constexpr int Bc = 2, Sc = 2048, Mc = 1024, Ec = 512, Hc = 8, DH = 64, Fc = 2048, Vc = 8192, Lc = 6;
constexpr int Nc = Bc * Sc;    // 4096 decoder rows
constexpr int NMc = Bc * Mc;   // 2048 encoder rows

__device__ __forceinline__ u16 f2b(float f) {
  __bf16 h = (__bf16)f;
  return __builtin_bit_cast(u16, h);
}

__device__ __forceinline__ f32x4 mfma16(bf16x8 a, bf16x8 b, f32x4 c) {
  return __builtin_amdgcn_mfma_f32_16x16x32_bf16(a, b, c, 0, 0, 0);
}

// ---------------------------------------------------------------------------
// One-shot f32->bf16 conversion of all weights/embeddings (8 segments).
// ---------------------------------------------------------------------------
constexpr int C0 = 1179648;
constexpr int C1 = C0 + 393216;
constexpr int C2 = C1 + 1179648;
constexpr int C3 = C2 + 393216;
constexpr int C4 = C3 + 1572864;
constexpr int C5 = C4 + 1572864;
constexpr int C6 = C5 + 1048576;
constexpr int C7 = C6 + 262144;        // total 7602176 = 29696*256

__global__ __launch_bounds__(256) void k_cvt_all(
    const float* __restrict__ s0, const float* __restrict__ s1,
    const float* __restrict__ s2, const float* __restrict__ s3,
    const float* __restrict__ s4, const float* __restrict__ s5,
    const float* __restrict__ s6, const float* __restrict__ s7,
    u16* __restrict__ d0, u16* __restrict__ d1, u16* __restrict__ d2,
    u16* __restrict__ d3, u16* __restrict__ d4, u16* __restrict__ d5,
    u16* __restrict__ d6, u16* __restrict__ d7) {
  int i = blockIdx.x * 256 + threadIdx.x;
  const float* s; u16* d; int off;
  if (i < C3) {
    if (i < C1) { if (i < C0) { s = s0; d = d0; off = i; }
                  else        { s = s1; d = d1; off = i - C0; } }
    else        { if (i < C2) { s = s2; d = d2; off = i - C1; }
                  else        { s = s3; d = d3; off = i - C2; } }
  } else {
    if (i < C5) { if (i < C4) { s = s4; d = d4; off = i - C3; }
                  else        { s = s5; d = d5; off = i - C4; } }
    else        { if (i < C6) { s = s6; d = d6; off = i - C5; }
                  else        { s = s7; d = d7; off = i - C6; } }
  }
  float4 v = ((const float4*)s)[off];
  unsigned lo = (unsigned)f2b(v.x) | ((unsigned)f2b(v.y) << 16);
  unsigned hi = (unsigned)f2b(v.z) | ((unsigned)f2b(v.w) << 16);
  ((uint2*)d)[off] = make_uint2(lo, hi);
}

// ---------------------------------------------------------------------------
__global__ __launch_bounds__(256) void k_embed(const int* __restrict__ seq,
                                               const float* __restrict__ emb,
                                               const float* __restrict__ pos,
                                               float* __restrict__ x,
                                               u16* __restrict__ xb) {
  int idx = blockIdx.x * 256 + threadIdx.x;
  int row = idx >> 9, e = idx & 511;
  int s = row & (Sc - 1);
  float v = emb[(size_t)seq[row] * Ec + e] + pos[(size_t)s * Ec + e];
  x[idx] = v;
  xb[idx] = f2b(v);
}

// ---------------------------------------------------------------------------
// GEMM body: bf16 MFMA, swizzled LDS via global_load_lds (pre-swizzled src).
// Proven 2-buffer pipeline: __syncthreads (vmcnt drain) + stage-next overlap.
// ---------------------------------------------------------------------------
template <int BM, int BN, int ACT>
__device__ __forceinline__ void gemm_body(const u16* __restrict__ A,
                                          const u16* __restrict__ W,
                                          const float* __restrict__ bias,
                                          float* __restrict__ C32,
                                          u16* __restrict__ Cb,
                                          int K, int Mo,
                                          size_t row0, size_t col0) {
  constexpr int WM = BM / 2, WN = BN / 2, FM = WM / 16, FN = WN / 16;
  __shared__ __attribute__((aligned(16))) u16 As[2][BM * 64];
  __shared__ __attribute__((aligned(16))) u16 Bs[2][BN * 64];
  const int tid = threadIdx.x;
  const int w = tid >> 6, l = tid & 63, l15 = l & 15, l4 = l >> 4;
  const int lr = l >> 3, lc = l & 7;
  const int wr = (w >> 1) * WM, wc = (w & 1) * WN;
  const u16* Ab = A + row0 * K;
  const u16* Wb = W + col0 * K;
  f32x4 acc[FM][FN] = {};

  auto stage = [&](int buf, int k0) {
#pragma unroll
    for (int i = 0; i < BM / 32; ++i) {
      int sw = lr ^ ((i * 4 + w) & 7);
      int row = i * 32 + w * 8 + lr;
      const u16* ga = Ab + (size_t)row * K + k0 + ((lc ^ sw) & 7) * 8;
      __builtin_amdgcn_global_load_lds((const __attribute__((address_space(1))) void*)ga,
          (__attribute__((address_space(3))) void*)((char*)As[buf] + (i * 32 + w * 8) * 128), 16, 0, 0);
    }
#pragma unroll
    for (int i = 0; i < BN / 32; ++i) {
      int sw = lr ^ ((i * 4 + w) & 7);
      int row = i * 32 + w * 8 + lr;
      const u16* gw = Wb + (size_t)row * K + k0 + ((lc ^ sw) & 7) * 8;
      __builtin_amdgcn_global_load_lds((const __attribute__((address_space(1))) void*)gw,
          (__attribute__((address_space(3))) void*)((char*)Bs[buf] + (i * 32 + w * 8) * 128), 16, 0, 0);
    }
  };
  auto compute = [&](int buf) {
    const u16* AsC = As[buf];
    const u16* BsC = Bs[buf];
#pragma unroll
    for (int ks = 0; ks < 2; ++ks) {
      bf16x8 af[FM], bfr[FN];
#pragma unroll
      for (int m = 0; m < FM; ++m) {
        int ra = wr + m * 16 + l15;
        int sw = (l15 & 7) ^ ((wr / 8 + 2 * m + (l15 >> 3)) & 7);
        af[m] = *(const bf16x8*)&AsC[ra * 64 + ((ks * 32 + l4 * 8) ^ (sw * 8))];
      }
#pragma unroll
      for (int n = 0; n < FN; ++n) {
        int rb = wc + n * 16 + l15;
        int sw = (l15 & 7) ^ ((wc / 8 + 2 * n + (l15 >> 3)) & 7);
        bfr[n] = *(const bf16x8*)&BsC[rb * 64 + ((ks * 32 + l4 * 8) ^ (sw * 8))];
      }
#pragma unroll
      for (int m = 0; m < FM; ++m)
#pragma unroll
        for (int n = 0; n < FN; ++n)
          acc[m][n] = mfma16(af[m], bfr[n], acc[m][n]);
    }
  };

  const int nk = K / 64;
  stage(0, 0);
  int cur = 0;
  for (int kt = 0; kt < nk; ++kt) {
    __syncthreads();                 // drains vmcnt: stage(cur) landed
    if (kt + 1 < nk) stage(cur ^ 1, (kt + 1) * 64);   // overlap w/ compute
    compute(cur);
    cur ^= 1;
  }

#pragma unroll
  for (int n = 0; n < FN; ++n) {
    size_t col = col0 + wc + n * 16 + l15;
    float bv = bias[col];
#pragma unroll
    for (int m = 0; m < FM; ++m)
#pragma unroll
      for (int r = 0; r < 4; ++r) {
        size_t row = row0 + wr + m * 16 + l4 * 4 + r;
        float v = acc[m][n][r] + bv;
        if (ACT) v = 0.5f * v * (1.f + erff(v * 0.70710678118654752f));
        if (C32) C32[row * Mo + col] = v;
        if (Cb) Cb[row * Mo + col] = f2b(v);
      }
  }
}

// XS=1: bijective XCD column-chunk swizzle (requires gridDim.x % 8 == 0):
// XCD (= linear id % 8) owns gx/8 consecutive B-column panels for all rows.
template <int BM, int BN, int ACT, int XS>
__global__ __launch_bounds__(256) void k_gemm_bf(const u16* __restrict__ A,
                                                 const u16* __restrict__ W,
                                                 const float* __restrict__ bias,
                                                 float* __restrict__ C32,
                                                 u16* __restrict__ Cb,
                                                 int K, int Mo) {
  int bx, by;
  if constexpr (XS) {
    int gx = gridDim.x;
    int bid = blockIdx.x + gx * blockIdx.y;
    int cw = gx >> 3;
    int xcd = bid & 7, j = bid >> 3;
    bx = xcd * cw + (j % cw);
    by = j / cw;
  } else {
    bx = blockIdx.x; by = blockIdx.y;
  }
  gemm_body<BM, BN, ACT>(A, W, bias, C32, Cb, K, Mo, (size_t)by * BM, (size_t)bx * BN);
}

// Merged cross-attention projections: job0 = q (4096x512), job1 = kv (2048x1024).
__global__ __launch_bounds__(256) void k_gemm_cross(
    const u16* __restrict__ A0, const u16* __restrict__ W0, const float* __restrict__ b0,
    u16* __restrict__ Co0,
    const u16* __restrict__ A1, const u16* __restrict__ W1, const float* __restrict__ b1,
    u16* __restrict__ Co1) {
  int bid = blockIdx.x;
  if (bid < 512) {                       // q: 64 row-tiles x 8 col-tiles
    int xcd = bid & 7, j = bid >> 3;
    gemm_body<64, 64, 0>(A0, W0, b0, nullptr, Co0, Ec, Ec, (size_t)j * 64, (size_t)xcd * 64);
  } else {                               // kv: 32 row-tiles x 16 col-tiles
    int r = bid - 512;
    int xcd = r & 7, j = r >> 3;
    int bx = xcd * 2 + (j & 1), by = j >> 1;
    gemm_body<64, 64, 0>(A1, W1, b1, nullptr, Co1, Ec, 2 * Ec, (size_t)by * 64, (size_t)bx * 64);
  }
}

// ---------------------------------------------------------------------------
// Flash attention fd2 + swapped QK^T (R8-proven, unchanged).
// ---------------------------------------------------------------------------
__global__ __launch_bounds__(512, 4) void k_flash(const u16* __restrict__ Qp, int sq,
                                                  const u16* __restrict__ Kp,
                                                  const u16* __restrict__ Vp, int skv,
                                                  u16* __restrict__ Op, int so,
                                                  int Sq, int Sk, int causal) {
  __shared__ __attribute__((aligned(16))) u16 Kst[4][64 * 64];
  __shared__ __attribute__((aligned(16))) u16 Vt[4][64 * 64];
  __shared__ __attribute__((aligned(16))) u16 Pl[8][16 * 64];
  const int tid = threadIdx.x;
  const int w = tid >> 6, l = tid & 63, l15 = l & 15, l4 = l >> 4;
  const int wq = w & 3, ws = w >> 2;
  const int lr = l >> 3, lc = l & 7;
  const int t256 = tid & 255;
  const int kk2 = t256 >> 3, dblk = tid & 7;
  const int nqt = Sq / 64, nkt = Sk / 64;
  const int h = blockIdx.y, b = blockIdx.z;
  const int bx = blockIdx.x;
  const int qi = causal ? ((b & 1) ? bx : (nqt - 1 - bx)) : bx;
  const int qt0 = qi * 64;
  const int nt = causal ? (qi + 1) : nkt;
  const int NI = (nt + 1) >> 1;
  const u16* Qb = Qp + (size_t)b * Sq * sq + h * DH;
  const u16* Kb = Kp + (size_t)b * Sk * skv + h * DH;
  const u16* Vb = Vp + (size_t)b * Sk * skv + h * DH;
  const int qg = qt0 + wq * 16 + l15;

  bf16x8 qf[2];
  {
    const u16* qp0 = Qb + (size_t)qg * sq + l4 * 8;
    qf[0] = *(const bf16x8*)(qp0);
    qf[1] = *(const bf16x8*)(qp0 + 32);
  }

  f32x4 oacc[4] = {};
  float ls = 0.f, Mx = -3e38f;
  const float CSC = 0.18033688011112042f;
  const int swp = (l15 & 7) ^ (l15 >> 3);

  u16x8 va, vbv;
  auto stageK = [&](int slot, int kt) {
#pragma unroll
    for (int i = 0; i < 2; ++i) {
      int sw = lr ^ ((i * 4 + wq) & 7);
      int row = i * 32 + wq * 8 + lr;
      const u16* src = Kb + (size_t)(kt + row) * skv + ((lc ^ sw) & 7) * 8;
      __builtin_amdgcn_global_load_lds((const __attribute__((address_space(1))) void*)src,
          (__attribute__((address_space(3))) void*)((char*)Kst[slot] + (i * 32 + wq * 8) * 128), 16, 0, 0);
    }
  };
  auto loadV = [&](int kt) {
    const u16* vp0 = Vb + (size_t)(kt + 2 * kk2) * skv + dblk * 8;
    va = *(const u16x8*)vp0;
    vbv = *(const u16x8*)(vp0 + skv);
  };
  auto writeV = [&](int slot) {
    char* Vb_ = (char*)Vt[slot];
#pragma unroll
    for (int j = 0; j < 8; ++j) {
      int d = dblk * 8 + j;
      int sw = (j ^ dblk) & 7;
      unsigned pk = (unsigned)va[j] | ((unsigned)vbv[j] << 16);
      *(unsigned*)(Vb_ + d * 128 + ((4 * kk2) ^ (sw << 4))) = pk;
    }
  };

  stageK(ws * 2, ws * 64);
  loadV(ws * 64);
  writeV(ws * 2);
  asm volatile("s_waitcnt lgkmcnt(0)" ::: "memory");
  __builtin_amdgcn_sched_barrier(0);
  __builtin_amdgcn_s_barrier();

  u16* Pw = Pl[w];
  for (int i = 0; i < NI; ++i) {
    const int t = 2 * i + ws;
    const int tn = t + 2;
    const int cur = ws * 2 + (i & 1);
    const int nxt = ws * 2 + ((i + 1) & 1);
    const bool haveNext = tn < nt;
    if (haveNext) {
      stageK(nxt, tn * 64);
      loadV(tn * 64);
    }
    if (t < nt) {
      const u16* KstC = Kst[cur];
      const u16* VtC = Vt[cur];

      f32x4 sf[4] = {};
      __builtin_amdgcn_s_setprio(1);
#pragma unroll
      for (int n = 0; n < 4; ++n) {
        int rk = n * 16 + l15;
        int sw = (l15 & 7) ^ ((2 * n + (l15 >> 3)) & 7);
#pragma unroll
        for (int ks = 0; ks < 2; ++ks) {
          bf16x8 kf = *(const bf16x8*)&KstC[rk * 64 + ((ks * 32 + l4 * 8) ^ (sw * 8))];
          sf[n] = mfma16(kf, qf[ks], sf[n]);
        }
      }
      __builtin_amdgcn_s_setprio(0);

      if (causal && t == nt - 1) {
#pragma unroll
        for (int n = 0; n < 4; ++n)
#pragma unroll
          for (int r = 0; r < 4; ++r) {
            int kcol = t * 64 + n * 16 + l4 * 4 + r;
            if (kcol > qg) sf[n][r] = -3e38f;
          }
      }

      float tm = fmaxf(fmaxf(fmaxf(sf[0][0], sf[0][1]), fmaxf(sf[0][2], sf[0][3])),
                       fmaxf(fmaxf(sf[1][0], sf[1][1]), fmaxf(sf[1][2], sf[1][3])));
      tm = fmaxf(tm, fmaxf(fmaxf(fmaxf(sf[2][0], sf[2][1]), fmaxf(sf[2][2], sf[2][3])),
                           fmaxf(fmaxf(sf[3][0], sf[3][1]), fmaxf(sf[3][2], sf[3][3]))));
      tm = fmaxf(tm, __shfl_xor(tm, 16, 64));
      tm = fmaxf(tm, __shfl_xor(tm, 32, 64));
      float Mn = fmaxf(Mx, tm);
      float al = exp2f((Mx - Mn) * CSC);
      Mx = Mn;
      float mxc = Mx * CSC;

      float rs = 0.f;
#pragma unroll
      for (int n = 0; n < 4; ++n) {
        float p0 = exp2f(sf[n][0] * CSC - mxc);
        float p1 = exp2f(sf[n][1] * CSC - mxc);
        float p2 = exp2f(sf[n][2] * CSC - mxc);
        float p3 = exp2f(sf[n][3] * CSC - mxc);
        rs += (p0 + p1) + (p2 + p3);
        unsigned w0 = (unsigned)f2b(p0) | ((unsigned)f2b(p1) << 16);
        unsigned w1 = (unsigned)f2b(p2) | ((unsigned)f2b(p3) << 16);
        int bb = (n * 32 + l4 * 8) ^ (swp << 4);
        *(unsigned*)((char*)Pw + l15 * 128 + bb) = w0;
        *(unsigned*)((char*)Pw + l15 * 128 + bb + 4) = w1;
      }
      rs += __shfl_xor(rs, 16, 64);
      rs += __shfl_xor(rs, 32, 64);
      ls = ls * al + rs;

      if (__any(al < 1.f)) {
        float a0 = __shfl(al, l4 * 4 + 0, 64);
        float a1 = __shfl(al, l4 * 4 + 1, 64);
        float a2 = __shfl(al, l4 * 4 + 2, 64);
        float a3 = __shfl(al, l4 * 4 + 3, 64);
#pragma unroll
        for (int n2 = 0; n2 < 4; ++n2) {
          oacc[n2][0] *= a0; oacc[n2][1] *= a1;
          oacc[n2][2] *= a2; oacc[n2][3] *= a3;
        }
      }

      asm volatile("s_waitcnt lgkmcnt(0)" ::: "memory");
      __builtin_amdgcn_sched_barrier(0);

      __builtin_amdgcn_s_setprio(1);
#pragma unroll
      for (int ks = 0; ks < 2; ++ks) {
        bf16x8 pf = *(const bf16x8*)((char*)Pw + l15 * 128 + ((ks * 64 + l4 * 16) ^ (swp << 4)));
#pragma unroll
        for (int n2 = 0; n2 < 4; ++n2) {
          int rd = n2 * 16 + l15;
          int sw = (l15 & 7) ^ ((2 * n2 + (l15 >> 3)) & 7);
          bf16x8 vf = *(const bf16x8*)((char*)VtC + rd * 128 + ((ks * 64 + l4 * 16) ^ (sw << 4)));
          oacc[n2] = mfma16(pf, vf, oacc[n2]);
        }
      }
      __builtin_amdgcn_s_setprio(0);
    }

    if (haveNext) writeV(nxt);
    asm volatile("s_waitcnt lgkmcnt(0)" ::: "memory");
    __builtin_amdgcn_sched_barrier(0);
    __builtin_amdgcn_s_barrier();
  }

  __syncthreads();
  float* OB = (float*)&Kst[0][0];
  float* ML = (float*)&Vt[0][0];
  if (l4 == 0) {
    ML[ws * 64 + wq * 16 + l15] = Mx;
    ML[128 + ws * 64 + wq * 16 + l15] = ls;
  }
  if (ws == 1) {
#pragma unroll
    for (int n2 = 0; n2 < 4; ++n2)
#pragma unroll
      for (int r = 0; r < 4; ++r)
        OB[(wq * 16 + l4 * 4 + r) * 64 + n2 * 16 + l15] = oacc[n2][r];
  }
  __syncthreads();
  if (ws == 0) {
    u16* Ob = Op + (size_t)b * Sq * so + h * DH;
#pragma unroll
    for (int r = 0; r < 4; ++r) {
      int qs = wq * 16 + l4 * 4 + r;
      float mA = ML[qs], mB = ML[64 + qs];
      float lA = ML[128 + qs], lB = ML[192 + qs];
      float M = fmaxf(mA, mB);
      float aA = exp2f((mA - M) * CSC);
      float aB = exp2f((mB - M) * CSC);
      float inv = 1.f / (lA * aA + lB * aB);
      int qrow = qt0 + qs;
#pragma unroll
      for (int n2 = 0; n2 < 4; ++n2) {
        float o = (oacc[n2][r] * aA + OB[qs * 64 + n2 * 16 + l15] * aB) * inv;
        Ob[(size_t)qrow * so + n2 * 16 + l15] = f2b(o);
      }
    }
  }
}

// ---------------------------------------------------------------------------
// Residual + LayerNorm: one WAVE per row, 4 rows/block. Thread l owns the
// CONTIGUOUS elements 8l..8l+7 (fixes R9/R10 bf16 interleave bug: f32 and
// bf16 stores now address the same elements).
// ---------------------------------------------------------------------------
__global__ __launch_bounds__(256) void k_res_ln(const float* __restrict__ xin,
                                                const float* __restrict__ rres,
                                                const float* __restrict__ g,
                                                const float* __restrict__ bet,
                                                float* __restrict__ outf,
                                                u16* __restrict__ outb,
                                                int has_res) {
  const int tid = threadIdx.x, w = tid >> 6, l = tid & 63;
  const int row = blockIdx.x * 4 + w;
  const float4* xr = (const float4*)(xin + (size_t)row * Ec);
  float4 a = xr[2 * l], c = xr[2 * l + 1];
  if (has_res) {
    const float4* rr = (const float4*)(rres + (size_t)row * Ec);
    float4 r0 = rr[2 * l], r1 = rr[2 * l + 1];
    a.x += r0.x; a.y += r0.y; a.z += r0.z; a.w += r0.w;
    c.x += r1.x; c.y += r1.y; c.z += r1.z; c.w += r1.w;
  }
  float s = (a.x + a.y) + (a.z + a.w) + (c.x + c.y) + (c.z + c.w);
#pragma unroll
  for (int o = 32; o; o >>= 1) s += __shfl_xor(s, o, 64);
  const float mean = s * (1.f / Ec);
  float d0 = a.x - mean, d1 = a.y - mean, d2 = a.z - mean, d3 = a.w - mean;
  float e0 = c.x - mean, e1 = c.y - mean, e2 = c.z - mean, e3 = c.w - mean;
  float vs = d0 * d0 + d1 * d1 + d2 * d2 + d3 * d3 +
             e0 * e0 + e1 * e1 + e2 * e2 + e3 * e3;
#pragma unroll
  for (int o = 32; o; o >>= 1) vs += __shfl_xor(vs, o, 64);
  const float inv = rsqrtf(vs * (1.f / Ec) + 1e-5f);
  float4 g0 = ((const float4*)g)[2 * l], g1 = ((const float4*)g)[2 * l + 1];
  float4 b0 = ((const float4*)bet)[2 * l], b1 = ((const float4*)bet)[2 * l + 1];
  float o0 = d0 * inv * g0.x + b0.x, o1 = d1 * inv * g0.y + b0.y;
  float o2 = d2 * inv * g0.z + b0.z, o3 = d3 * inv * g0.w + b0.w;
  float o4 = e0 * inv * g1.x + b1.x, o5 = e1 * inv * g1.y + b1.y;
  float o6 = e2 * inv * g1.z + b1.z, o7 = e3 * inv * g1.w + b1.w;
  float4* orow = (float4*)(outf + (size_t)row * Ec);
  orow[2 * l] = make_float4(o0, o1, o2, o3);
  orow[2 * l + 1] = make_float4(o4, o5, o6, o7);
  if (outb) {
    uint4 pk;
    pk.x = (unsigned)f2b(o0) | ((unsigned)f2b(o1) << 16);
    pk.y = (unsigned)f2b(o2) | ((unsigned)f2b(o3) << 16);
    pk.z = (unsigned)f2b(o4) | ((unsigned)f2b(o5) << 16);
    pk.w = (unsigned)f2b(o6) | ((unsigned)f2b(o7) << 16);
    ((uint4*)(outb + (size_t)row * Ec))[l] = pk;   // elements 8l..8l+7 ✓
  }
}

// ---------------------------------------------------------------------------
extern "C" void kernel_launch(void* const* d_in, const int* in_sizes, int n_in,
                              void* d_out, int out_size, void* d_ws, size_t ws_size,
                              hipStream_t stream) {
  const float* encoded      = (const float*)d_in[0];
  const int*   seq          = (const int*)d_in[1];
  const float* input_embed  = (const float*)d_in[2];
  const float* pos_embed    = (const float*)d_in[3];
  const float* output_bias  = (const float*)d_in[4];
  const float* self_in_w    = (const float*)d_in[5];
  const float* self_in_b    = (const float*)d_in[6];
  const float* self_out_w   = (const float*)d_in[7];
  const float* self_out_b   = (const float*)d_in[8];
  const float* cross_in_w   = (const float*)d_in[9];
  const float* cross_in_b   = (const float*)d_in[10];
  const float* cross_out_w  = (const float*)d_in[11];
  const float* cross_out_b  = (const float*)d_in[12];
  const float* self_norm_g  = (const float*)d_in[13];
  const float* self_norm_b  = (const float*)d_in[14];
  const float* cross_norm_g = (const float*)d_in[15];
  const float* cross_norm_b = (const float*)d_in[16];
  const float* mlp_norm_g   = (const float*)d_in[17];
  const float* mlp_norm_b   = (const float*)d_in[18];
  const float* lin1_w       = (const float*)d_in[19];
  const float* lin1_b       = (const float*)d_in[20];
  const float* lin2_w       = (const float*)d_in[21];
  const float* lin2_b       = (const float*)d_in[22];
  const float* final_norm_g = (const float*)d_in[23];
  const float* final_norm_b = (const float*)d_in[24];

  char* oc = (char*)d_out;
  auto take = [&](size_t bytes) { char* p = oc; oc += bytes; return p; };
  u16* wsi  = (u16*)take((size_t)Lc * 3 * Ec * Ec * 2);
  u16* wso  = (u16*)take((size_t)Lc * Ec * Ec * 2);
  u16* wci  = (u16*)take((size_t)Lc * 3 * Ec * Ec * 2);
  u16* wco  = (u16*)take((size_t)Lc * Ec * Ec * 2);
  u16* wl1  = (u16*)take((size_t)Lc * Fc * Ec * 2);
  u16* wl2  = (u16*)take((size_t)Lc * Ec * Fc * 2);
  u16* encb = (u16*)take((size_t)NMc * Ec * 2);
  float* xs  = (float*)take((size_t)Nc * Ec * 4);
  float* ys  = (float*)take((size_t)Nc * Ec * 4);
  float* tmp = (float*)take((size_t)Nc * Ec * 4);
  u16* xbf  = (u16*)take((size_t)Nc * Ec * 2);
  u16* qkvb = (u16*)take((size_t)Nc * 3 * Ec * 2);
  u16* ctxb = (u16*)take((size_t)Nc * Ec * 2);
  u16* qxb  = (u16*)take((size_t)Nc * Ec * 2);
  u16* kvb  = (u16*)take((size_t)NMc * 2 * Ec * 2);
  u16* hbf  = (u16*)take((size_t)Nc * Fc * 2);
  u16* xfb  = (u16*)d_ws;
  u16* embb = (u16*)((char*)d_ws + (size_t)Nc * Ec * 2);

  const dim3 blk(256);
  k_cvt_all<<<dim3(29696), blk, 0, stream>>>(
      self_in_w, self_out_w, cross_in_w, cross_out_w, lin1_w, lin2_w,
      input_embed, encoded, wsi, wso, wci, wco, wl1, wl2, embb, encb);

  k_embed<<<dim3(Nc * Ec / 256), blk, 0, stream>>>(seq, input_embed, pos_embed, xs, xbf);

  const dim3 gAttn(Sc / 64, Hc, Bc);
  const dim3 blkA(512);
  const dim3 gLN(Nc / 4);
  for (int l = 0; l < Lc; ++l) {
    const u16* wsi_l = wsi + (size_t)l * 3 * Ec * Ec;
    const u16* wci_l = wci + (size_t)l * 3 * Ec * Ec;
    // self attention
    k_gemm_bf<128, 64, 0, 1><<<dim3(3 * Ec / 64, Nc / 128), blk, 0, stream>>>(
        xbf, wsi_l, self_in_b + (size_t)l * 3 * Ec, nullptr, qkvb, Ec, 3 * Ec);
    k_flash<<<gAttn, blkA, 0, stream>>>(qkvb, 3 * Ec, qkvb + Ec, qkvb + 2 * Ec, 3 * Ec,
                                        ctxb, Ec, Sc, Sc, 1);
    k_gemm_bf<64, 64, 0, 1><<<dim3(Ec / 64, Nc / 64), blk, 0, stream>>>(
        ctxb, wso + (size_t)l * Ec * Ec, self_out_b + (size_t)l * Ec, tmp, nullptr, Ec, Ec);
    k_res_ln<<<gLN, blk, 0, stream>>>(xs, tmp, self_norm_g + (size_t)l * Ec,
                                      self_norm_b + (size_t)l * Ec, ys, xbf, 1);
    // cross attention: q + kv projections merged in one dispatch
    k_gemm_cross<<<dim3(1024), blk, 0, stream>>>(
        xbf, wci_l, cross_in_b + (size_t)l * 3 * Ec, qxb,
        encb, wci_l + (size_t)Ec * Ec, cross_in_b + (size_t)l * 3 * Ec + Ec, kvb);
    k_flash<<<gAttn, blkA, 0, stream>>>(qxb, Ec, kvb, kvb + Ec, 2 * Ec,
                                        ctxb, Ec, Sc, Mc, 0);
    k_gemm_bf<64, 64, 0, 1><<<dim3(Ec / 64, Nc / 64), blk, 0, stream>>>(
        ctxb, wco + (size_t)l * Ec * Ec, cross_out_b + (size_t)l * Ec, tmp, nullptr, Ec, Ec);
    k_res_ln<<<gLN, blk, 0, stream>>>(ys, tmp, cross_norm_g + (size_t)l * Ec,
                                      cross_norm_b + (size_t)l * Ec, xs, xbf, 1);
    // MLP
    k_gemm_bf<128, 128, 1, 1><<<dim3(Fc / 128, Nc / 128), blk, 0, stream>>>(
        xbf, wl1 + (size_t)l * Fc * Ec, lin1_b + (size_t)l * Fc, nullptr, hbf, Ec, Fc);
    k_gemm_bf<64, 64, 0, 1><<<dim3(Ec / 64, Nc / 64), blk, 0, stream>>>(
        hbf, wl2 + (size_t)l * Ec * Fc, lin2_b + (size_t)l * Ec, tmp, nullptr, Fc, Ec);
    k_res_ln<<<gLN, blk, 0, stream>>>(xs, tmp, mlp_norm_g + (size_t)l * Ec,
                                      mlp_norm_b + (size_t)l * Ec, xs, xbf, 1);
  }

  k_res_ln<<<gLN, blk, 0, stream>>>(xs, nullptr, final_norm_g, final_norm_b, xs, xfb, 0);
  k_gemm_bf<128, 128, 0, 1><<<dim3(Vc / 128, Nc / 128), blk, 0, stream>>>(
      xfb, embb, output_bias, (float*)d_out, nullptr, Ec, Vc);
}

// Round 12
// 1121.652 us; speedup vs baseline: 1.4393x; 1.0169x over previous
//
#include <hip/hip_runtime.h>
#include <math.h>

typedef unsigned short u16;
typedef __attribute__((ext_vector_type(8))) unsigned short u16x8;
typedef __attribute__((ext_vector_type(8))) __bf16 bf16x8;
typedef __attribute__((ext_vector_type(4))) float f32x4;

constexpr int Bc = 2, Sc = 2048, Mc = 1024, Ec = 512, Hc = 8, DH = 64, Fc = 2048, Vc = 8192, Lc = 6;
constexpr int Nc = Bc * Sc;    // 4096 decoder rows
constexpr int NMc = Bc * Mc;   // 2048 encoder rows

__device__ __forceinline__ u16 f2b(float f) {
  __bf16 h = (__bf16)f;
  return __builtin_bit_cast(u16, h);
}
__device__ __forceinline__ float b2f_lo(unsigned w) { return __builtin_bit_cast(float, w << 16); }
__device__ __forceinline__ float b2f_hi(unsigned w) { return __builtin_bit_cast(float, w & 0xFFFF0000u); }

__device__ __forceinline__ f32x4 mfma16(bf16x8 a, bf16x8 b, f32x4 c) {
  return __builtin_amdgcn_mfma_f32_16x16x32_bf16(a, b, c, 0, 0, 0);
}

// ---------------------------------------------------------------------------
// One-shot f32->bf16 conversion of all weights/embeddings (8 segments) PLUS
// the token embedding (segment 9: gather + positional add, 4 elems/thread).
// ---------------------------------------------------------------------------
constexpr int C0 = 1179648;
constexpr int C1 = C0 + 393216;
constexpr int C2 = C1 + 1179648;
constexpr int C3 = C2 + 393216;
constexpr int C4 = C3 + 1572864;
constexpr int C5 = C4 + 1572864;
constexpr int C6 = C5 + 1048576;
constexpr int C7 = C6 + 262144;        // cvt total 7602176 = 29696*256
constexpr int C8 = C7 + Nc * Ec / 4;   // + embed 524288 -> grid 31744

__global__ __launch_bounds__(256) void k_cvt_all(
    const float* __restrict__ s0, const float* __restrict__ s1,
    const float* __restrict__ s2, const float* __restrict__ s3,
    const float* __restrict__ s4, const float* __restrict__ s5,
    const float* __restrict__ s6, const float* __restrict__ s7,
    u16* __restrict__ d0, u16* __restrict__ d1, u16* __restrict__ d2,
    u16* __restrict__ d3, u16* __restrict__ d4, u16* __restrict__ d5,
    u16* __restrict__ d6, u16* __restrict__ d7,
    const int* __restrict__ seq, const float* __restrict__ pos,
    float* __restrict__ xs, u16* __restrict__ xb) {
  int i = blockIdx.x * 256 + threadIdx.x;
  if (i >= C7) {                        // embed segment
    int j = i - C7;                     // 0 .. Nc*Ec/4-1
    int idx0 = j * 4;
    int row = idx0 >> 9, e = idx0 & 511;
    int s = row & (Sc - 1);
    float4 ev = *(const float4*)(s6 + (size_t)seq[row] * Ec + e);
    float4 pv = *(const float4*)(pos + (size_t)s * Ec + e);
    float4 v = make_float4(ev.x + pv.x, ev.y + pv.y, ev.z + pv.z, ev.w + pv.w);
    ((float4*)xs)[j] = v;
    unsigned lo = (unsigned)f2b(v.x) | ((unsigned)f2b(v.y) << 16);
    unsigned hi = (unsigned)f2b(v.z) | ((unsigned)f2b(v.w) << 16);
    ((uint2*)xb)[j] = make_uint2(lo, hi);
    return;
  }
  const float* s; u16* d; int off;
  if (i < C3) {
    if (i < C1) { if (i < C0) { s = s0; d = d0; off = i; }
                  else        { s = s1; d = d1; off = i - C0; } }
    else        { if (i < C2) { s = s2; d = d2; off = i - C1; }
                  else        { s = s3; d = d3; off = i - C2; } }
  } else {
    if (i < C5) { if (i < C4) { s = s4; d = d4; off = i - C3; }
                  else        { s = s5; d = d5; off = i - C4; } }
    else        { if (i < C6) { s = s6; d = d6; off = i - C5; }
                  else        { s = s7; d = d7; off = i - C6; } }
  }
  float4 v = ((const float4*)s)[off];
  unsigned lo = (unsigned)f2b(v.x) | ((unsigned)f2b(v.y) << 16);
  unsigned hi = (unsigned)f2b(v.z) | ((unsigned)f2b(v.w) << 16);
  ((uint2*)d)[off] = make_uint2(lo, hi);
}

// ---------------------------------------------------------------------------
// GEMM body: bf16 MFMA, swizzled LDS via global_load_lds (pre-swizzled src).
// Proven 2-buffer pipeline: __syncthreads (vmcnt drain) + stage-next overlap.
// ---------------------------------------------------------------------------
template <int BM, int BN, int ACT>
__device__ __forceinline__ void gemm_body(const u16* __restrict__ A,
                                          const u16* __restrict__ W,
                                          const float* __restrict__ bias,
                                          float* __restrict__ C32,
                                          u16* __restrict__ Cb,
                                          int K, int Mo,
                                          size_t row0, size_t col0) {
  constexpr int WM = BM / 2, WN = BN / 2, FM = WM / 16, FN = WN / 16;
  __shared__ __attribute__((aligned(16))) u16 As[2][BM * 64];
  __shared__ __attribute__((aligned(16))) u16 Bs[2][BN * 64];
  const int tid = threadIdx.x;
  const int w = tid >> 6, l = tid & 63, l15 = l & 15, l4 = l >> 4;
  const int lr = l >> 3, lc = l & 7;
  const int wr = (w >> 1) * WM, wc = (w & 1) * WN;
  const u16* Ab = A + row0 * K;
  const u16* Wb = W + col0 * K;
  f32x4 acc[FM][FN] = {};

  auto stage = [&](int buf, int k0) {
#pragma unroll
    for (int i = 0; i < BM / 32; ++i) {
      int sw = lr ^ ((i * 4 + w) & 7);
      int row = i * 32 + w * 8 + lr;
      const u16* ga = Ab + (size_t)row * K + k0 + ((lc ^ sw) & 7) * 8;
      __builtin_amdgcn_global_load_lds((const __attribute__((address_space(1))) void*)ga,
          (__attribute__((address_space(3))) void*)((char*)As[buf] + (i * 32 + w * 8) * 128), 16, 0, 0);
    }
#pragma unroll
    for (int i = 0; i < BN / 32; ++i) {
      int sw = lr ^ ((i * 4 + w) & 7);
      int row = i * 32 + w * 8 + lr;
      const u16* gw = Wb + (size_t)row * K + k0 + ((lc ^ sw) & 7) * 8;
      __builtin_amdgcn_global_load_lds((const __attribute__((address_space(1))) void*)gw,
          (__attribute__((address_space(3))) void*)((char*)Bs[buf] + (i * 32 + w * 8) * 128), 16, 0, 0);
    }
  };
  auto compute = [&](int buf) {
    const u16* AsC = As[buf];
    const u16* BsC = Bs[buf];
#pragma unroll
    for (int ks = 0; ks < 2; ++ks) {
      bf16x8 af[FM], bfr[FN];
#pragma unroll
      for (int m = 0; m < FM; ++m) {
        int ra = wr + m * 16 + l15;
        int sw = (l15 & 7) ^ ((wr / 8 + 2 * m + (l15 >> 3)) & 7);
        af[m] = *(const bf16x8*)&AsC[ra * 64 + ((ks * 32 + l4 * 8) ^ (sw * 8))];
      }
#pragma unroll
      for (int n = 0; n < FN; ++n) {
        int rb = wc + n * 16 + l15;
        int sw = (l15 & 7) ^ ((wc / 8 + 2 * n + (l15 >> 3)) & 7);
        bfr[n] = *(const bf16x8*)&BsC[rb * 64 + ((ks * 32 + l4 * 8) ^ (sw * 8))];
      }
#pragma unroll
      for (int m = 0; m < FM; ++m)
#pragma unroll
        for (int n = 0; n < FN; ++n)
          acc[m][n] = mfma16(af[m], bfr[n], acc[m][n]);
    }
  };

  const int nk = K / 64;
  stage(0, 0);
  int cur = 0;
  for (int kt = 0; kt < nk; ++kt) {
    __syncthreads();                 // drains vmcnt: stage(cur) landed
    if (kt + 1 < nk) stage(cur ^ 1, (kt + 1) * 64);   // overlap w/ compute
    compute(cur);
    cur ^= 1;
  }

#pragma unroll
  for (int n = 0; n < FN; ++n) {
    size_t col = col0 + wc + n * 16 + l15;
    float bv = bias[col];
#pragma unroll
    for (int m = 0; m < FM; ++m)
#pragma unroll
      for (int r = 0; r < 4; ++r) {
        size_t row = row0 + wr + m * 16 + l4 * 4 + r;
        float v = acc[m][n][r] + bv;
        if (ACT) v = 0.5f * v * (1.f + erff(v * 0.70710678118654752f));
        if (C32) C32[row * Mo + col] = v;
        if (Cb) Cb[row * Mo + col] = f2b(v);
      }
  }
}

// XS=1: bijective XCD column-chunk swizzle (requires gridDim.x % 8 == 0).
template <int BM, int BN, int ACT, int XS>
__global__ __launch_bounds__(256) void k_gemm_bf(const u16* __restrict__ A,
                                                 const u16* __restrict__ W,
                                                 const float* __restrict__ bias,
                                                 float* __restrict__ C32,
                                                 u16* __restrict__ Cb,
                                                 int K, int Mo) {
  int bx, by;
  if constexpr (XS) {
    int gx = gridDim.x;
    int bid = blockIdx.x + gx * blockIdx.y;
    int cw = gx >> 3;
    int xcd = bid & 7, j = bid >> 3;
    bx = xcd * cw + (j % cw);
    by = j / cw;
  } else {
    bx = blockIdx.x; by = blockIdx.y;
  }
  gemm_body<BM, BN, ACT>(A, W, bias, C32, Cb, K, Mo, (size_t)by * BM, (size_t)bx * BN);
}

// Merged cross-attention projections: job0 = q (4096x512), job1 = kv (2048x1024).
__global__ __launch_bounds__(256) void k_gemm_cross(
    const u16* __restrict__ A0, const u16* __restrict__ W0, const float* __restrict__ b0,
    u16* __restrict__ Co0,
    const u16* __restrict__ A1, const u16* __restrict__ W1, const float* __restrict__ b1,
    u16* __restrict__ Co1) {
  int bid = blockIdx.x;
  if (bid < 512) {                       // q: 64 row-tiles x 8 col-tiles
    int xcd = bid & 7, j = bid >> 3;
    gemm_body<64, 64, 0>(A0, W0, b0, nullptr, Co0, Ec, Ec, (size_t)j * 64, (size_t)xcd * 64);
  } else {                               // kv: 32 row-tiles x 16 col-tiles
    int r = bid - 512;
    int xcd = r & 7, j = r >> 3;
    int bx = xcd * 2 + (j & 1), by = j >> 1;
    gemm_body<64, 64, 0>(A1, W1, b1, nullptr, Co1, Ec, 2 * Ec, (size_t)by * 64, (size_t)bx * 64);
  }
}

// ---------------------------------------------------------------------------
// Flash attention fd2 + swapped QK^T (R8-proven, unchanged).
// ---------------------------------------------------------------------------
__global__ __launch_bounds__(512, 4) void k_flash(const u16* __restrict__ Qp, int sq,
                                                  const u16* __restrict__ Kp,
                                                  const u16* __restrict__ Vp, int skv,
                                                  u16* __restrict__ Op, int so,
                                                  int Sq, int Sk, int causal) {
  __shared__ __attribute__((aligned(16))) u16 Kst[4][64 * 64];
  __shared__ __attribute__((aligned(16))) u16 Vt[4][64 * 64];
  __shared__ __attribute__((aligned(16))) u16 Pl[8][16 * 64];
  const int tid = threadIdx.x;
  const int w = tid >> 6, l = tid & 63, l15 = l & 15, l4 = l >> 4;
  const int wq = w & 3, ws = w >> 2;
  const int lr = l >> 3, lc = l & 7;
  const int t256 = tid & 255;
  const int kk2 = t256 >> 3, dblk = tid & 7;
  const int nqt = Sq / 64, nkt = Sk / 64;
  const int h = blockIdx.y, b = blockIdx.z;
  const int bx = blockIdx.x;
  const int qi = causal ? ((b & 1) ? bx : (nqt - 1 - bx)) : bx;
  const int qt0 = qi * 64;
  const int nt = causal ? (qi + 1) : nkt;
  const int NI = (nt + 1) >> 1;
  const u16* Qb = Qp + (size_t)b * Sq * sq + h * DH;
  const u16* Kb = Kp + (size_t)b * Sk * skv + h * DH;
  const u16* Vb = Vp + (size_t)b * Sk * skv + h * DH;
  const int qg = qt0 + wq * 16 + l15;

  bf16x8 qf[2];
  {
    const u16* qp0 = Qb + (size_t)qg * sq + l4 * 8;
    qf[0] = *(const bf16x8*)(qp0);
    qf[1] = *(const bf16x8*)(qp0 + 32);
  }

  f32x4 oacc[4] = {};
  float ls = 0.f, Mx = -3e38f;
  const float CSC = 0.18033688011112042f;
  const int swp = (l15 & 7) ^ (l15 >> 3);

  u16x8 va, vbv;
  auto stageK = [&](int slot, int kt) {
#pragma unroll
    for (int i = 0; i < 2; ++i) {
      int sw = lr ^ ((i * 4 + wq) & 7);
      int row = i * 32 + wq * 8 + lr;
      const u16* src = Kb + (size_t)(kt + row) * skv + ((lc ^ sw) & 7) * 8;
      __builtin_amdgcn_global_load_lds((const __attribute__((address_space(1))) void*)src,
          (__attribute__((address_space(3))) void*)((char*)Kst[slot] + (i * 32 + wq * 8) * 128), 16, 0, 0);
    }
  };
  auto loadV = [&](int kt) {
    const u16* vp0 = Vb + (size_t)(kt + 2 * kk2) * skv + dblk * 8;
    va = *(const u16x8*)vp0;
    vbv = *(const u16x8*)(vp0 + skv);
  };
  auto writeV = [&](int slot) {
    char* Vb_ = (char*)Vt[slot];
#pragma unroll
    for (int j = 0; j < 8; ++j) {
      int d = dblk * 8 + j;
      int sw = (j ^ dblk) & 7;
      unsigned pk = (unsigned)va[j] | ((unsigned)vbv[j] << 16);
      *(unsigned*)(Vb_ + d * 128 + ((4 * kk2) ^ (sw << 4))) = pk;
    }
  };

  stageK(ws * 2, ws * 64);
  loadV(ws * 64);
  writeV(ws * 2);
  asm volatile("s_waitcnt lgkmcnt(0)" ::: "memory");
  __builtin_amdgcn_sched_barrier(0);
  __builtin_amdgcn_s_barrier();

  u16* Pw = Pl[w];
  for (int i = 0; i < NI; ++i) {
    const int t = 2 * i + ws;
    const int tn = t + 2;
    const int cur = ws * 2 + (i & 1);
    const int nxt = ws * 2 + ((i + 1) & 1);
    const bool haveNext = tn < nt;
    if (haveNext) {
      stageK(nxt, tn * 64);
      loadV(tn * 64);
    }
    if (t < nt) {
      const u16* KstC = Kst[cur];
      const u16* VtC = Vt[cur];

      f32x4 sf[4] = {};
      __builtin_amdgcn_s_setprio(1);
#pragma unroll
      for (int n = 0; n < 4; ++n) {
        int rk = n * 16 + l15;
        int sw = (l15 & 7) ^ ((2 * n + (l15 >> 3)) & 7);
#pragma unroll
        for (int ks = 0; ks < 2; ++ks) {
          bf16x8 kf = *(const bf16x8*)&KstC[rk * 64 + ((ks * 32 + l4 * 8) ^ (sw * 8))];
          sf[n] = mfma16(kf, qf[ks], sf[n]);
        }
      }
      __builtin_amdgcn_s_setprio(0);

      if (causal && t == nt - 1) {
#pragma unroll
        for (int n = 0; n < 4; ++n)
#pragma unroll
          for (int r = 0; r < 4; ++r) {
            int kcol = t * 64 + n * 16 + l4 * 4 + r;
            if (kcol > qg) sf[n][r] = -3e38f;
          }
      }

      float tm = fmaxf(fmaxf(fmaxf(sf[0][0], sf[0][1]), fmaxf(sf[0][2], sf[0][3])),
                       fmaxf(fmaxf(sf[1][0], sf[1][1]), fmaxf(sf[1][2], sf[1][3])));
      tm = fmaxf(tm, fmaxf(fmaxf(fmaxf(sf[2][0], sf[2][1]), fmaxf(sf[2][2], sf[2][3])),
                           fmaxf(fmaxf(sf[3][0], sf[3][1]), fmaxf(sf[3][2], sf[3][3]))));
      tm = fmaxf(tm, __shfl_xor(tm, 16, 64));
      tm = fmaxf(tm, __shfl_xor(tm, 32, 64));
      float Mn = fmaxf(Mx, tm);
      float al = exp2f((Mx - Mn) * CSC);
      Mx = Mn;
      float mxc = Mx * CSC;

      float rs = 0.f;
#pragma unroll
      for (int n = 0; n < 4; ++n) {
        float p0 = exp2f(sf[n][0] * CSC - mxc);
        float p1 = exp2f(sf[n][1] * CSC - mxc);
        float p2 = exp2f(sf[n][2] * CSC - mxc);
        float p3 = exp2f(sf[n][3] * CSC - mxc);
        rs += (p0 + p1) + (p2 + p3);
        unsigned w0 = (unsigned)f2b(p0) | ((unsigned)f2b(p1) << 16);
        unsigned w1 = (unsigned)f2b(p2) | ((unsigned)f2b(p3) << 16);
        int bb = (n * 32 + l4 * 8) ^ (swp << 4);
        *(unsigned*)((char*)Pw + l15 * 128 + bb) = w0;
        *(unsigned*)((char*)Pw + l15 * 128 + bb + 4) = w1;
      }
      rs += __shfl_xor(rs, 16, 64);
      rs += __shfl_xor(rs, 32, 64);
      ls = ls * al + rs;

      if (__any(al < 1.f)) {
        float a0 = __shfl(al, l4 * 4 + 0, 64);
        float a1 = __shfl(al, l4 * 4 + 1, 64);
        float a2 = __shfl(al, l4 * 4 + 2, 64);
        float a3 = __shfl(al, l4 * 4 + 3, 64);
#pragma unroll
        for (int n2 = 0; n2 < 4; ++n2) {
          oacc[n2][0] *= a0; oacc[n2][1] *= a1;
          oacc[n2][2] *= a2; oacc[n2][3] *= a3;
        }
      }

      asm volatile("s_waitcnt lgkmcnt(0)" ::: "memory");
      __builtin_amdgcn_sched_barrier(0);

      __builtin_amdgcn_s_setprio(1);
#pragma unroll
      for (int ks = 0; ks < 2; ++ks) {
        bf16x8 pf = *(const bf16x8*)((char*)Pw + l15 * 128 + ((ks * 64 + l4 * 16) ^ (swp << 4)));
#pragma unroll
        for (int n2 = 0; n2 < 4; ++n2) {
          int rd = n2 * 16 + l15;
          int sw = (l15 & 7) ^ ((2 * n2 + (l15 >> 3)) & 7);
          bf16x8 vf = *(const bf16x8*)((char*)VtC + rd * 128 + ((ks * 64 + l4 * 16) ^ (sw << 4)));
          oacc[n2] = mfma16(pf, vf, oacc[n2]);
        }
      }
      __builtin_amdgcn_s_setprio(0);
    }

    if (haveNext) writeV(nxt);
    asm volatile("s_waitcnt lgkmcnt(0)" ::: "memory");
    __builtin_amdgcn_sched_barrier(0);
    __builtin_amdgcn_s_barrier();
  }

  __syncthreads();
  float* OB = (float*)&Kst[0][0];
  float* ML = (float*)&Vt[0][0];
  if (l4 == 0) {
    ML[ws * 64 + wq * 16 + l15] = Mx;
    ML[128 + ws * 64 + wq * 16 + l15] = ls;
  }
  if (ws == 1) {
#pragma unroll
    for (int n2 = 0; n2 < 4; ++n2)
#pragma unroll
      for (int r = 0; r < 4; ++r)
        OB[(wq * 16 + l4 * 4 + r) * 64 + n2 * 16 + l15] = oacc[n2][r];
  }
  __syncthreads();
  if (ws == 0) {
    u16* Ob = Op + (size_t)b * Sq * so + h * DH;
#pragma unroll
    for (int r = 0; r < 4; ++r) {
      int qs = wq * 16 + l4 * 4 + r;
      float mA = ML[qs], mB = ML[64 + qs];
      float lA = ML[128 + qs], lB = ML[192 + qs];
      float M = fmaxf(mA, mB);
      float aA = exp2f((mA - M) * CSC);
      float aB = exp2f((mB - M) * CSC);
      float inv = 1.f / (lA * aA + lB * aB);
      int qrow = qt0 + qs;
#pragma unroll
      for (int n2 = 0; n2 < 4; ++n2) {
        float o = (oacc[n2][r] * aA + OB[qs * 64 + n2 * 16 + l15] * aB) * inv;
        Ob[(size_t)qrow * so + n2 * 16 + l15] = f2b(o);
      }
    }
  }
}

// ---------------------------------------------------------------------------
// Residual + LayerNorm: one WAVE per row, 4 rows/block; thread l owns
// contiguous elements 8l..8l+7. Residual branch input is now bf16 (rres).
// outf may be null (final LN).
// ---------------------------------------------------------------------------
__global__ __launch_bounds__(256) void k_res_ln(const float* __restrict__ xin,
                                                const u16* __restrict__ rres,
                                                const float* __restrict__ g,
                                                const float* __restrict__ bet,
                                                float* __restrict__ outf,
                                                u16* __restrict__ outb,
                                                int has_res) {
  const int tid = threadIdx.x, w = tid >> 6, l = tid & 63;
  const int row = blockIdx.x * 4 + w;
  const float4* xr = (const float4*)(xin + (size_t)row * Ec);
  float4 a = xr[2 * l], c = xr[2 * l + 1];
  if (has_res) {
    uint4 rv = ((const uint4*)(rres + (size_t)row * Ec))[l];  // elems 8l..8l+7
    a.x += b2f_lo(rv.x); a.y += b2f_hi(rv.x);
    a.z += b2f_lo(rv.y); a.w += b2f_hi(rv.y);
    c.x += b2f_lo(rv.z); c.y += b2f_hi(rv.z);
    c.z += b2f_lo(rv.w); c.w += b2f_hi(rv.w);
  }
  float s = (a.x + a.y) + (a.z + a.w) + (c.x + c.y) + (c.z + c.w);
#pragma unroll
  for (int o = 32; o; o >>= 1) s += __shfl_xor(s, o, 64);
  const float mean = s * (1.f / Ec);
  float d0 = a.x - mean, d1 = a.y - mean, d2 = a.z - mean, d3 = a.w - mean;
  float e0 = c.x - mean, e1 = c.y - mean, e2 = c.z - mean, e3 = c.w - mean;
  float vs = d0 * d0 + d1 * d1 + d2 * d2 + d3 * d3 +
             e0 * e0 + e1 * e1 + e2 * e2 + e3 * e3;
#pragma unroll
  for (int o = 32; o; o >>= 1) vs += __shfl_xor(vs, o, 64);
  const float inv = rsqrtf(vs * (1.f / Ec) + 1e-5f);
  float4 g0 = ((const float4*)g)[2 * l], g1 = ((const float4*)g)[2 * l + 1];
  float4 b0 = ((const float4*)bet)[2 * l], b1 = ((const float4*)bet)[2 * l + 1];
  float o0 = d0 * inv * g0.x + b0.x, o1 = d1 * inv * g0.y + b0.y;
  float o2 = d2 * inv * g0.z + b0.z, o3 = d3 * inv * g0.w + b0.w;
  float o4 = e0 * inv * g1.x + b1.x, o5 = e1 * inv * g1.y + b1.y;
  float o6 = e2 * inv * g1.z + b1.z, o7 = e3 * inv * g1.w + b1.w;
  if (outf) {
    float4* orow = (float4*)(outf + (size_t)row * Ec);
    orow[2 * l] = make_float4(o0, o1, o2, o3);
    orow[2 * l + 1] = make_float4(o4, o5, o6, o7);
  }
  if (outb) {
    uint4 pk;
    pk.x = (unsigned)f2b(o0) | ((unsigned)f2b(o1) << 16);
    pk.y = (unsigned)f2b(o2) | ((unsigned)f2b(o3) << 16);
    pk.z = (unsigned)f2b(o4) | ((unsigned)f2b(o5) << 16);
    pk.w = (unsigned)f2b(o6) | ((unsigned)f2b(o7) << 16);
    ((uint4*)(outb + (size_t)row * Ec))[l] = pk;
  }
}

// ---------------------------------------------------------------------------
extern "C" void kernel_launch(void* const* d_in, const int* in_sizes, int n_in,
                              void* d_out, int out_size, void* d_ws, size_t ws_size,
                              hipStream_t stream) {
  const float* encoded      = (const float*)d_in[0];
  const int*   seq          = (const int*)d_in[1];
  const float* input_embed  = (const float*)d_in[2];
  const float* pos_embed    = (const float*)d_in[3];
  const float* output_bias  = (const float*)d_in[4];
  const float* self_in_w    = (const float*)d_in[5];
  const float* self_in_b    = (const float*)d_in[6];
  const float* self_out_w   = (const float*)d_in[7];
  const float* self_out_b   = (const float*)d_in[8];
  const float* cross_in_w   = (const float*)d_in[9];
  const float* cross_in_b   = (const float*)d_in[10];
  const float* cross_out_w  = (const float*)d_in[11];
  const float* cross_out_b  = (const float*)d_in[12];
  const float* self_norm_g  = (const float*)d_in[13];
  const float* self_norm_b  = (const float*)d_in[14];
  const float* cross_norm_g = (const float*)d_in[15];
  const float* cross_norm_b = (const float*)d_in[16];
  const float* mlp_norm_g   = (const float*)d_in[17];
  const float* mlp_norm_b   = (const float*)d_in[18];
  const float* lin1_w       = (const float*)d_in[19];
  const float* lin1_b       = (const float*)d_in[20];
  const float* lin2_w       = (const float*)d_in[21];
  const float* lin2_b       = (const float*)d_in[22];
  const float* final_norm_g = (const float*)d_in[23];
  const float* final_norm_b = (const float*)d_in[24];

  char* oc = (char*)d_out;
  auto take = [&](size_t bytes) { char* p = oc; oc += bytes; return p; };
  u16* wsi  = (u16*)take((size_t)Lc * 3 * Ec * Ec * 2);
  u16* wso  = (u16*)take((size_t)Lc * Ec * Ec * 2);
  u16* wci  = (u16*)take((size_t)Lc * 3 * Ec * Ec * 2);
  u16* wco  = (u16*)take((size_t)Lc * Ec * Ec * 2);
  u16* wl1  = (u16*)take((size_t)Lc * Fc * Ec * 2);
  u16* wl2  = (u16*)take((size_t)Lc * Ec * Fc * 2);
  u16* encb = (u16*)take((size_t)NMc * Ec * 2);
  float* xs  = (float*)take((size_t)Nc * Ec * 4);
  float* ys  = (float*)take((size_t)Nc * Ec * 4);
  u16* tmpb = (u16*)take((size_t)Nc * Ec * 2);
  u16* xbf  = (u16*)take((size_t)Nc * Ec * 2);
  u16* qkvb = (u16*)take((size_t)Nc * 3 * Ec * 2);
  u16* ctxb = (u16*)take((size_t)Nc * Ec * 2);
  u16* qxb  = (u16*)take((size_t)Nc * Ec * 2);
  u16* kvb  = (u16*)take((size_t)NMc * 2 * Ec * 2);
  u16* hbf  = (u16*)take((size_t)Nc * Fc * 2);
  u16* xfb  = (u16*)d_ws;
  u16* embb = (u16*)((char*)d_ws + (size_t)Nc * Ec * 2);

  const dim3 blk(256);
  k_cvt_all<<<dim3(C8 / 256), blk, 0, stream>>>(
      self_in_w, self_out_w, cross_in_w, cross_out_w, lin1_w, lin2_w,
      input_embed, encoded, wsi, wso, wci, wco, wl1, wl2, embb, encb,
      seq, pos_embed, xs, xbf);

  const dim3 gAttn(Sc / 64, Hc, Bc);
  const dim3 blkA(512);
  const dim3 gLN(Nc / 4);
  for (int l = 0; l < Lc; ++l) {
    const u16* wsi_l = wsi + (size_t)l * 3 * Ec * Ec;
    const u16* wci_l = wci + (size_t)l * 3 * Ec * Ec;
    // self attention
    k_gemm_bf<128, 64, 0, 1><<<dim3(3 * Ec / 64, Nc / 128), blk, 0, stream>>>(
        xbf, wsi_l, self_in_b + (size_t)l * 3 * Ec, nullptr, qkvb, Ec, 3 * Ec);
    k_flash<<<gAttn, blkA, 0, stream>>>(qkvb, 3 * Ec, qkvb + Ec, qkvb + 2 * Ec, 3 * Ec,
                                        ctxb, Ec, Sc, Sc, 1);
    k_gemm_bf<64, 64, 0, 1><<<dim3(Ec / 64, Nc / 64), blk, 0, stream>>>(
        ctxb, wso + (size_t)l * Ec * Ec, self_out_b + (size_t)l * Ec, nullptr, tmpb, Ec, Ec);
    k_res_ln<<<gLN, blk, 0, stream>>>(xs, tmpb, self_norm_g + (size_t)l * Ec,
                                      self_norm_b + (size_t)l * Ec, ys, xbf, 1);
    // cross attention: q + kv projections merged in one dispatch
    k_gemm_cross<<<dim3(1024), blk, 0, stream>>>(
        xbf, wci_l, cross_in_b + (size_t)l * 3 * Ec, qxb,
        encb, wci_l + (size_t)Ec * Ec, cross_in_b + (size_t)l * 3 * Ec + Ec, kvb);
    k_flash<<<gAttn, blkA, 0, stream>>>(qxb, Ec, kvb, kvb + Ec, 2 * Ec,
                                        ctxb, Ec, Sc, Mc, 0);
    k_gemm_bf<64, 64, 0, 1><<<dim3(Ec / 64, Nc / 64), blk, 0, stream>>>(
        ctxb, wco + (size_t)l * Ec * Ec, cross_out_b + (size_t)l * Ec, nullptr, tmpb, Ec, Ec);
    k_res_ln<<<gLN, blk, 0, stream>>>(ys, tmpb, cross_norm_g + (size_t)l * Ec,
                                      cross_norm_b + (size_t)l * Ec, xs, xbf, 1);
    // MLP
    k_gemm_bf<128, 128, 1, 1><<<dim3(Fc / 128, Nc / 128), blk, 0, stream>>>(
        xbf, wl1 + (size_t)l * Fc * Ec, lin1_b + (size_t)l * Fc, nullptr, hbf, Ec, Fc);
    k_gemm_bf<64, 64, 0, 1><<<dim3(Ec / 64, Nc / 64), blk, 0, stream>>>(
        hbf, wl2 + (size_t)l * Ec * Fc, lin2_b + (size_t)l * Ec, nullptr, tmpb, Fc, Ec);
    k_res_ln<<<gLN, blk, 0, stream>>>(xs, tmpb, mlp_norm_g + (size_t)l * Ec,
                                      mlp_norm_b + (size_t)l * Ec, xs, xbf, 1);
  }

  k_res_ln<<<gLN, blk, 0, stream>>>(xs, nullptr, final_norm_g, final_norm_b, nullptr, xfb, 0);
  k_gemm_bf<128, 128, 0, 1><<<dim3(Vc / 128, Nc / 128), blk, 0, stream>>>(
      xfb, embb, output_bias, (float*)d_out, nullptr, Ec, Vc);
}